// Round 8
// baseline (336.795 us; speedup 1.0000x reference)
//
#include <hip/hip_runtime.h>

#define N_NODES 50000
#define N_EDGES 800000
#define NHID    256
#define NRES_P1 101

#define NB_SCAN     196        // ceil(50000/256)
#define POOL_BLOCKS 2048       // fused agg2+pool grid
#define LDK         40         // LDS k-stride (u16): 80B, 16B-aligned, 2-way banks

typedef unsigned short u16;
typedef __attribute__((ext_vector_type(8))) short short8;   // 8 bf16
typedef __attribute__((ext_vector_type(4))) float f32x4;

static __device__ __forceinline__ unsigned f2bf(float f) {  // RNE -> low 16
    unsigned u = __float_as_uint(f);
    return (u + 0x7FFF + ((u >> 16) & 1)) >> 16;
}
static __device__ __forceinline__ float bflo(unsigned p) {
    return __uint_as_float(p << 16);
}
static __device__ __forceinline__ float bfhi(unsigned p) {
    return __uint_as_float(p & 0xffff0000u);
}

// ---------------------------------------------------------------- graph prep

__global__ void k_count(const int* __restrict__ ei,
                        int* __restrict__ deg, int* __restrict__ indeg) {
    int tid = blockIdx.x * 256 + threadIdx.x;
    if (tid >= N_EDGES / 4) return;
    int4 r = *(const int4*)&ei[tid * 4];
    int4 c = *(const int4*)&ei[N_EDGES + tid * 4];
    atomicAdd(&deg[r.x], 1); atomicAdd(&deg[r.y], 1);
    atomicAdd(&deg[r.z], 1); atomicAdd(&deg[r.w], 1);
    atomicAdd(&indeg[c.x], 1); atomicAdd(&indeg[c.y], 1);
    atomicAdd(&indeg[c.z], 1); atomicAdd(&indeg[c.w], 1);
}

// 3-kernel exclusive scan of (indeg+1) -> rowptr (+cursor); dis fused in scan3

__global__ __launch_bounds__(256) void k_scan1(const int* __restrict__ cnt,
                                               int* __restrict__ bsum) {
    int t = threadIdx.x, lane = t & 63, wid = t >> 6;
    int i = blockIdx.x * 256 + t;
    int v = (i < N_NODES) ? cnt[i] + 1 : 0;      // +1 = self-loop
#pragma unroll
    for (int off = 32; off > 0; off >>= 1) v += __shfl_down(v, off, 64);
    __shared__ int ws[4];
    if (lane == 0) ws[wid] = v;
    __syncthreads();
    if (t == 0) bsum[blockIdx.x] = ws[0] + ws[1] + ws[2] + ws[3];
}

__global__ __launch_bounds__(256) void k_scan2(const int* __restrict__ bsum,
                                               int* __restrict__ bpre) {
    __shared__ int s[256];
    int t = threadIdx.x;
    int v0 = (t < NB_SCAN) ? bsum[t] : 0;
    s[t] = v0;
    __syncthreads();
    for (int off = 1; off < 256; off <<= 1) {
        int v = (t >= off) ? s[t - off] : 0;
        __syncthreads();
        s[t] += v;
        __syncthreads();
    }
    if (t < NB_SCAN) bpre[t] = s[t] - v0;   // exclusive
}

__global__ __launch_bounds__(256) void k_scan3(
    const int* __restrict__ cnt, const int* __restrict__ bpre,
    const int* __restrict__ deg, int* __restrict__ rowptr,
    int* __restrict__ cursor, float* __restrict__ dis) {
    int t = threadIdx.x, lane = t & 63, wid = t >> 6;
    int i = blockIdx.x * 256 + t;
    int v = (i < N_NODES) ? cnt[i] + 1 : 0;
    int sc = v;
#pragma unroll
    for (int off = 1; off < 64; off <<= 1) {
        int y = __shfl_up(sc, off, 64);
        if (lane >= off) sc += y;
    }
    __shared__ int wsum[4], wexcl[4];
    if (lane == 63) wsum[wid] = sc;
    __syncthreads();
    if (t == 0) {
        int r = 0;
#pragma unroll
        for (int w = 0; w < 4; ++w) { wexcl[w] = r; r += wsum[w]; }
    }
    __syncthreads();
    if (i < N_NODES) {
        int excl = bpre[blockIdx.x] + wexcl[wid] + sc - v;
        rowptr[i] = excl;
        cursor[i] = excl;
        dis[i] = rsqrtf((float)(deg[i] + 1));
    }
}

__global__ void k_fill(const int* __restrict__ ei,
                       int* __restrict__ cursor, int* __restrict__ srcl) {
    int tid = blockIdx.x * 256 + threadIdx.x;
    if (tid < N_EDGES / 4) {
        int4 r = *(const int4*)&ei[tid * 4];
        int4 c = *(const int4*)&ei[N_EDGES + tid * 4];
        int p;
        p = atomicAdd(&cursor[c.x], 1); srcl[p] = r.x;
        p = atomicAdd(&cursor[c.y], 1); srcl[p] = r.y;
        p = atomicAdd(&cursor[c.z], 1); srcl[p] = r.z;
        p = atomicAdd(&cursor[c.w], 1); srcl[p] = r.w;
    } else if (tid < N_EDGES / 4 + N_NODES / 4) {
        int n4 = (tid - N_EDGES / 4) * 4;
#pragma unroll
        for (int j = 0; j < 4; ++j) {
            int n = n4 + j;
            int p = atomicAdd(&cursor[n], 1);
            srcl[p] = n;                        // self loop
        }
    }
}

// both weight transposes in one dispatch: WT[n][k] = bf16(W[k][n])
__global__ void k_prep_w2(const float* __restrict__ W1, const float* __restrict__ W2,
                          u16* __restrict__ W1T, u16* __restrict__ W2T) {
    int tid = blockIdx.x * 256 + threadIdx.x;    // 16384
    const float* W = (tid < 8192) ? W1 : W2;
    u16* WT = (tid < 8192) ? W1T : W2T;
    int id = tid & 8191;
    int n = id >> 5, k8 = (id & 31) << 3;
    u16 tmp[8];
#pragma unroll
    for (int i = 0; i < 8; ++i) tmp[i] = (u16)f2bf(W[(size_t)(k8 + i) * 256 + n]);
    *(uint4*)&WT[(size_t)n * 256 + k8] = *(uint4*)tmp;
}

// ------------------------------------------------------------- MFMA GEMM
// out[m][n] = bf16( dis[m] * ( sum_k A[m][k] * W[k][n] + bias[n] ) )
// BM=128, BN=256 (full N, single pass over A), BK=32, 256 thr = 2x2 waves,
// wave-tile 64x128 (acc 4x8 frags). SPLIT: A = concat(x,feat) f32, converted
// to bf16 during staging (fused cvtA).

template <bool SPLIT>
__global__ __launch_bounds__(256, 2) void k_gemm_mfma(
    const void* __restrict__ A0v, const float* __restrict__ A1,
    const u16* __restrict__ WT, const float* __restrict__ bias,
    const float* __restrict__ dis, u16* __restrict__ out, int M) {
    __shared__ u16 As[128][LDK];
    __shared__ u16 Bs[256][LDK];
    const int t = threadIdx.x;
    const int m0 = blockIdx.x * 128;
    const int lane = t & 63, wave = t >> 6;
    const int wm = wave & 1, wn = wave >> 1;
    const int lr = lane & 15, kg = lane >> 4;

    f32x4 acc[4][8] = {};

    for (int k0 = 0; k0 < 256; k0 += 32) {
        // A tile: 128 rows x 32 k = 512 chunks of 8 bf16; 2 per thread
#pragma unroll
        for (int i = 0; i < 2; ++i) {
            int idx = i * 256 + t;
            int row = idx >> 2, kc = (idx & 3) << 3;
            int grow = m0 + row;
            uint4 pk = {0u, 0u, 0u, 0u};
            if (grow < M) {
                if (SPLIT) {
                    int k = k0 + kc;            // 8-aligned, never straddles 128
                    const float* src = (k < 128)
                        ? ((const float*)A0v + (size_t)grow * 128 + k)
                        : (A1 + (size_t)grow * 128 + (k - 128));
                    float4 f0 = *(const float4*)src;
                    float4 f1 = *(const float4*)(src + 4);
                    pk.x = f2bf(f0.x) | (f2bf(f0.y) << 16);
                    pk.y = f2bf(f0.z) | (f2bf(f0.w) << 16);
                    pk.z = f2bf(f1.x) | (f2bf(f1.y) << 16);
                    pk.w = f2bf(f1.z) | (f2bf(f1.w) << 16);
                } else {
                    pk = *(const uint4*)((const u16*)A0v +
                                         (size_t)grow * 256 + k0 + kc);
                }
            }
            *(uint4*)&As[row][kc] = pk;
        }
        // B tile: 256 n-rows x 32 k = 1024 chunks; 4 per thread
#pragma unroll
        for (int i = 0; i < 4; ++i) {
            int idx = i * 256 + t;
            int n = idx >> 2, kc = (idx & 3) << 3;
            *(uint4*)&Bs[n][kc] = *(const uint4*)&WT[(size_t)n * 256 + k0 + kc];
        }
        __syncthreads();
        short8 af[4], bf[8];
#pragma unroll
        for (int mi = 0; mi < 4; ++mi)
            af[mi] = *(const short8*)&As[wm * 64 + mi * 16 + lr][kg * 8];
#pragma unroll
        for (int ni = 0; ni < 8; ++ni)
            bf[ni] = *(const short8*)&Bs[wn * 128 + ni * 16 + lr][kg * 8];
#pragma unroll
        for (int mi = 0; mi < 4; ++mi)
#pragma unroll
            for (int ni = 0; ni < 8; ++ni)
                acc[mi][ni] = __builtin_amdgcn_mfma_f32_16x16x32_bf16(
                    af[mi], bf[ni], acc[mi][ni], 0, 0, 0);
        __syncthreads();
    }

    const int orow = m0 + wm * 64;
    const int ocol = wn * 128;
#pragma unroll
    for (int mi = 0; mi < 4; ++mi) {
#pragma unroll
        for (int r = 0; r < 4; ++r) {
            int row = orow + mi * 16 + kg * 4 + r;
            if (row >= M) continue;
            float d = dis[row];
#pragma unroll
            for (int ni = 0; ni < 8; ++ni) {
                int col = ocol + ni * 16 + lr;
                out[(size_t)row * 256 + col] =
                    (u16)f2bf(d * (acc[mi][ni][r] + bias[col]));
            }
        }
    }
}

// ----------------------------------------------------------- CSR aggregation
// Wave per dst. Per 64-edge chunk: ONE coalesced srcl load -> LDS, padded
// with N_NODES (a dedicated ZERO row in hs). Inner loop: fixed 32-edge
// batches, 16 uint4 loads per half-wave issued back-to-back, branch-free.
// Dummy edges gather the zero row (L1-resident) and add 0 — no serialized
// tail round-trips.

static __device__ __forceinline__ void addv4(uint4 v, float* a) {
    a[0] += bflo(v.x); a[1] += bfhi(v.x);
    a[2] += bflo(v.y); a[3] += bfhi(v.y);
    a[4] += bflo(v.z); a[5] += bfhi(v.z);
    a[6] += bflo(v.w); a[7] += bfhi(v.w);
}

static __device__ __forceinline__ void gather_batch16(
    const int* __restrict__ p, const u16* __restrict__ base, float* a) {
    int4 q0 = *(const int4*)p;              // ds_read_b128 broadcast
    int4 q1 = *(const int4*)(p + 4);
    int4 q2 = *(const int4*)(p + 8);
    int4 q3 = *(const int4*)(p + 12);
    uint4 v0  = *(const uint4*)(base + (size_t)q0.x * 256);
    uint4 v1  = *(const uint4*)(base + (size_t)q0.y * 256);
    uint4 v2  = *(const uint4*)(base + (size_t)q0.z * 256);
    uint4 v3  = *(const uint4*)(base + (size_t)q0.w * 256);
    uint4 v4  = *(const uint4*)(base + (size_t)q1.x * 256);
    uint4 v5  = *(const uint4*)(base + (size_t)q1.y * 256);
    uint4 v6  = *(const uint4*)(base + (size_t)q1.z * 256);
    uint4 v7  = *(const uint4*)(base + (size_t)q1.w * 256);
    uint4 v8  = *(const uint4*)(base + (size_t)q2.x * 256);
    uint4 v9  = *(const uint4*)(base + (size_t)q2.y * 256);
    uint4 v10 = *(const uint4*)(base + (size_t)q2.z * 256);
    uint4 v11 = *(const uint4*)(base + (size_t)q2.w * 256);
    uint4 v12 = *(const uint4*)(base + (size_t)q3.x * 256);
    uint4 v13 = *(const uint4*)(base + (size_t)q3.y * 256);
    uint4 v14 = *(const uint4*)(base + (size_t)q3.z * 256);
    uint4 v15 = *(const uint4*)(base + (size_t)q3.w * 256);
    addv4(v0, a);  addv4(v1, a);  addv4(v2, a);  addv4(v3, a);
    addv4(v4, a);  addv4(v5, a);  addv4(v6, a);  addv4(v7, a);
    addv4(v8, a);  addv4(v9, a);  addv4(v10, a); addv4(v11, a);
    addv4(v12, a); addv4(v13, a); addv4(v14, a); addv4(v15, a);
}

__global__ __launch_bounds__(256) void k_agg(
    const int* __restrict__ rowptr, const int* __restrict__ rowend,
    const int* __restrict__ srcl, const u16* __restrict__ hs,
    const float* __restrict__ dis, u16* __restrict__ out) {
    __shared__ int idxb[4][64];
    int wave = threadIdx.x >> 6;
    int lane = threadIdx.x & 63;
    int half = lane >> 5;
    int ch8 = (lane & 31) << 3;
    int dst = blockIdx.x * 4 + wave;
    if (dst >= N_NODES) return;
    int s = rowptr[dst], e = rowend[dst];
    const u16* base = hs + ch8;
    float a[8] = {0.f, 0.f, 0.f, 0.f, 0.f, 0.f, 0.f, 0.f};
    for (int k0 = s; k0 < e; k0 += 64) {
        int kk = k0 + lane;
        idxb[wave][lane] = (kk < e) ? __builtin_nontemporal_load(&srcl[kk])
                                    : N_NODES;           // zero row
        int nn = min(64, e - k0);
        for (int j = 0; j < nn; j += 32)
            gather_batch16(&idxb[wave][j + half * 16], base, a);
    }
#pragma unroll
    for (int j = 0; j < 8; ++j) a[j] += __shfl_xor(a[j], 32, 64);
    if (half == 0) {
        float d = dis[dst];
        uint4 p;
        p.x = f2bf(fmaxf(a[0] * d, 0.f)) | (f2bf(fmaxf(a[1] * d, 0.f)) << 16);
        p.y = f2bf(fmaxf(a[2] * d, 0.f)) | (f2bf(fmaxf(a[3] * d, 0.f)) << 16);
        p.z = f2bf(fmaxf(a[4] * d, 0.f)) | (f2bf(fmaxf(a[5] * d, 0.f)) << 16);
        p.w = f2bf(fmaxf(a[6] * d, 0.f)) | (f2bf(fmaxf(a[7] * d, 0.f)) << 16);
        *(uint4*)&out[(size_t)dst * 256 + ch8] = p;
    }
}

// agg2 + global max pool fused (g pre-zeroed; relu folded since max >= 0)

__global__ __launch_bounds__(256) void k_agg_pool(
    const int* __restrict__ rowptr, const int* __restrict__ rowend,
    const int* __restrict__ srcl, const u16* __restrict__ hs,
    const float* __restrict__ dis, float* __restrict__ g) {
    __shared__ int idxb[4][64];
    int wave = threadIdx.x >> 6;
    int lane = threadIdx.x & 63;
    int half = lane >> 5;
    int ch8 = (lane & 31) << 3;
    const u16* base = hs + ch8;
    float m[8] = {0.f, 0.f, 0.f, 0.f, 0.f, 0.f, 0.f, 0.f};
    for (int dst = blockIdx.x * 4 + wave; dst < N_NODES;
         dst += POOL_BLOCKS * 4) {
        int s = rowptr[dst], e = rowend[dst];
        float a[8] = {0.f, 0.f, 0.f, 0.f, 0.f, 0.f, 0.f, 0.f};
        for (int k0 = s; k0 < e; k0 += 64) {
            int kk = k0 + lane;
            idxb[wave][lane] = (kk < e) ? __builtin_nontemporal_load(&srcl[kk])
                                        : N_NODES;       // zero row
            int nn = min(64, e - k0);
            for (int j = 0; j < nn; j += 32)
                gather_batch16(&idxb[wave][j + half * 16], base, a);
        }
        float d = dis[dst];
#pragma unroll
        for (int j = 0; j < 8; ++j) {
            float v = (a[j] + __shfl_xor(a[j], 32, 64)) * d;
            m[j] = fmaxf(m[j], v);
        }
    }
    __shared__ float lm[4][256];
    if (half == 0) {
#pragma unroll
        for (int j = 0; j < 8; ++j) lm[wave][ch8 + j] = m[j];
    }
    __syncthreads();
    int t = threadIdx.x;
    float v = fmaxf(fmaxf(lm[0][t], lm[1][t]), fmaxf(lm[2][t], lm[3][t]));
    atomicMax((int*)&g[t], __float_as_int(v));
}

// --------------------------------------------------------------------- head

__global__ __launch_bounds__(128) void k_head(
    const float* __restrict__ g, const float* __restrict__ Wp,
    const float* __restrict__ bp, const float* __restrict__ Wq,
    const float* __restrict__ bq, float* __restrict__ out) {
    __shared__ float sg[NHID];
    __shared__ float red[128];
    int t = threadIdx.x;
    sg[t] = g[t];
    sg[t + 128] = g[t + 128];
    __syncthreads();

    float v = 0.0f;
    if (t < NRES_P1) {
        float acc = bp[t];
        for (int k = 0; k < NHID; ++k) acc = fmaf(sg[k], Wp[k * NRES_P1 + t], acc);
        out[t] = acc;
        v = acc;
    }
    red[t] = (t < NRES_P1) ? v : -1e30f;
    __syncthreads();
#pragma unroll
    for (int off = 64; off > 0; off >>= 1) {
        if (t < off) red[t] = fmaxf(red[t], red[t + off]);
        __syncthreads();
    }
    float mx = red[0];
    __syncthreads();
    float ex = (t < NRES_P1) ? expf(v - mx) : 0.0f;
    red[t] = ex;
    __syncthreads();
#pragma unroll
    for (int off = 64; off > 0; off >>= 1) {
        if (t < off) red[t] += red[t + off];
        __syncthreads();
    }
    float sum = red[0];
    if (t < NRES_P1) out[NRES_P1 + t] = ex / sum;

    if (t < 64) {
        float a = fmaf(sg[t], Wq[t], 0.f);
        a = fmaf(sg[t + 64],  Wq[t + 64],  a);
        a = fmaf(sg[t + 128], Wq[t + 128], a);
        a = fmaf(sg[t + 192], Wq[t + 192], a);
#pragma unroll
        for (int off = 32; off > 0; off >>= 1) a += __shfl_down(a, off, 64);
        if (t == 0) out[2 * NRES_P1] = a + bq[0];
    }
}

// -------------------------------------------------------------------- launch

static inline size_t align256(size_t x) { return (x + 255) & ~size_t(255); }

extern "C" void kernel_launch(void* const* d_in, const int* in_sizes, int n_in,
                              void* d_out, int out_size, void* d_ws,
                              size_t ws_size, hipStream_t stream) {
    (void)in_sizes; (void)n_in; (void)out_size; (void)ws_size;
    const float* x    = (const float*)d_in[0];
    const float* feat = (const float*)d_in[1];
    const int*   ei   = (const int*)d_in[2];   // int32 (harness-converted)
    const float* W1   = (const float*)d_in[3];
    const float* b1   = (const float*)d_in[4];
    const float* W2   = (const float*)d_in[5];
    const float* b2   = (const float*)d_in[6];
    const float* Wp   = (const float*)d_in[7];
    const float* bp   = (const float*)d_in[8];
    const float* Wq   = (const float*)d_in[9];
    const float* bq   = (const float*)d_in[10];
    float* out = (float*)d_out;

    char* ws = (char*)d_ws;
    size_t off = 0;
    auto alloc = [&](size_t bytes) {
        void* p = ws + off;
        off = align256(off + bytes);
        return p;
    };
    int*   deg    = (int*)alloc(4ull * N_NODES);
    int*   indeg  = (int*)alloc(4ull * N_NODES);
    int*   rowptr = (int*)alloc(4ull * (N_NODES + 1));
    int*   cursor = (int*)alloc(4ull * (N_NODES + 1));
    int*   srcl   = (int*)alloc(4ull * (N_EDGES + N_NODES));
    int*   bsum   = (int*)alloc(4ull * NB_SCAN);
    int*   bpre   = (int*)alloc(4ull * NB_SCAN);
    float* dis    = (float*)alloc(4ull * N_NODES);
    float* g      = (float*)alloc(4ull * NHID);
    u16*   W1T    = (u16*)alloc(2ull * 256 * 256);
    u16*   W2T    = (u16*)alloc(2ull * 256 * 256);
    u16*   buf1   = (u16*)alloc(2ull * (N_NODES + 1) * 256);   // h1 (+zero row)
    u16*   buf2   = (u16*)alloc(2ull * (N_NODES + 1) * 256);   // h2
    u16*   buf3   = (u16*)alloc(2ull * (N_NODES + 1) * 256);   // h3 (+zero row)

    hipMemsetAsync(deg,   0, 4ull * N_NODES, stream);
    hipMemsetAsync(indeg, 0, 4ull * N_NODES, stream);
    hipMemsetAsync(g,     0, 4ull * NHID,    stream);
    // zero rows (gather padding targets)
    hipMemsetAsync(buf1 + (size_t)N_NODES * 256, 0, 512, stream);
    hipMemsetAsync(buf3 + (size_t)N_NODES * 256, 0, 512, stream);

    k_prep_w2<<<64, 256, 0, stream>>>(W1, W2, W1T, W2T);
    k_count<<<(N_EDGES / 4 + 255) / 256, 256, 0, stream>>>(ei, deg, indeg);
    k_scan1<<<NB_SCAN, 256, 0, stream>>>(indeg, bsum);
    k_scan2<<<1, 256, 0, stream>>>(bsum, bpre);
    k_scan3<<<NB_SCAN, 256, 0, stream>>>(indeg, bpre, deg, rowptr, cursor, dis);
    k_fill<<<(N_EDGES / 4 + N_NODES / 4 + 255) / 256, 256, 0, stream>>>(
        ei, cursor, srcl);

    const int gblocks = (N_NODES + 127) / 128;
    // conv1 linear (A = concat(x,feat) f32, converted in staging)
    k_gemm_mfma<true><<<gblocks, 256, 0, stream>>>(x, feat, W1T, b1, dis,
                                                   buf1, N_NODES);
    // agg1: h2 = bf16(relu(dis .* gather-sum(h1)))
    k_agg<<<(N_NODES + 3) / 4, 256, 0, stream>>>(rowptr, cursor, srcl,
                                                 buf1, dis, buf2);
    // conv2 linear
    k_gemm_mfma<false><<<gblocks, 256, 0, stream>>>(buf2, nullptr, W2T, b2,
                                                    dis, buf3, N_NODES);
    // agg2 + fused global max pool -> g
    k_agg_pool<<<POOL_BLOCKS, 256, 0, stream>>>(rowptr, cursor, srcl,
                                                buf3, dis, g);

    k_head<<<1, 128, 0, stream>>>(g, Wp, bp, Wq, bq, out);
}

// Round 9
// 321.807 us; speedup vs baseline: 1.0466x; 1.0466x over previous
//
#include <hip/hip_runtime.h>

#define N_NODES 50000
#define N_EDGES 800000
#define NHID    256
#define NRES_P1 101

#define NB_SCAN     196        // ceil(50000/256)
#define POOL_BLOCKS 512        // fused agg2+pool grid (u64 atomics capped)
#define LDK         40         // LDS k-stride (u16): 80B, 16B-aligned, 2-way banks

typedef unsigned short u16;
typedef unsigned char  u8;
typedef unsigned long long ull;
typedef __attribute__((ext_vector_type(8))) short short8;   // 8 bf16
typedef __attribute__((ext_vector_type(4))) float f32x4;

static __device__ __forceinline__ unsigned f2bf(float f) {  // RNE -> low 16
    unsigned u = __float_as_uint(f);
    return (u + 0x7FFF + ((u >> 16) & 1)) >> 16;
}
static __device__ __forceinline__ float bflo(unsigned p) {
    return __uint_as_float(p << 16);
}
static __device__ __forceinline__ float bfhi(unsigned p) {
    return __uint_as_float(p & 0xffff0000u);
}
static __device__ __forceinline__ u8 f2fp8(float f) {       // HW e4m3 (OCP)
    return (u8)(__builtin_amdgcn_cvt_pk_fp8_f32(f, f, 0, false) & 0xff);
}

// ---------------------------------------------------------------- graph prep

__global__ void k_count(const int* __restrict__ ei,
                        int* __restrict__ deg, int* __restrict__ indeg) {
    int tid = blockIdx.x * 256 + threadIdx.x;
    if (tid >= N_EDGES / 4) return;
    int4 r = *(const int4*)&ei[tid * 4];
    int4 c = *(const int4*)&ei[N_EDGES + tid * 4];
    atomicAdd(&deg[r.x], 1); atomicAdd(&deg[r.y], 1);
    atomicAdd(&deg[r.z], 1); atomicAdd(&deg[r.w], 1);
    atomicAdd(&indeg[c.x], 1); atomicAdd(&indeg[c.y], 1);
    atomicAdd(&indeg[c.z], 1); atomicAdd(&indeg[c.w], 1);
}

// 3-kernel exclusive scan of (indeg+1) -> rowptr (+cursor); dis fused in scan3

__global__ __launch_bounds__(256) void k_scan1(const int* __restrict__ cnt,
                                               int* __restrict__ bsum) {
    int t = threadIdx.x, lane = t & 63, wid = t >> 6;
    int i = blockIdx.x * 256 + t;
    int v = (i < N_NODES) ? cnt[i] + 1 : 0;      // +1 = self-loop
#pragma unroll
    for (int off = 32; off > 0; off >>= 1) v += __shfl_down(v, off, 64);
    __shared__ int ws[4];
    if (lane == 0) ws[wid] = v;
    __syncthreads();
    if (t == 0) bsum[blockIdx.x] = ws[0] + ws[1] + ws[2] + ws[3];
}

__global__ __launch_bounds__(256) void k_scan2(const int* __restrict__ bsum,
                                               int* __restrict__ bpre) {
    __shared__ int s[256];
    int t = threadIdx.x;
    int v0 = (t < NB_SCAN) ? bsum[t] : 0;
    s[t] = v0;
    __syncthreads();
    for (int off = 1; off < 256; off <<= 1) {
        int v = (t >= off) ? s[t - off] : 0;
        __syncthreads();
        s[t] += v;
        __syncthreads();
    }
    if (t < NB_SCAN) bpre[t] = s[t] - v0;   // exclusive
}

__global__ __launch_bounds__(256) void k_scan3(
    const int* __restrict__ cnt, const int* __restrict__ bpre,
    const int* __restrict__ deg, int* __restrict__ rowptr,
    int* __restrict__ cursor, float* __restrict__ dis) {
    int t = threadIdx.x, lane = t & 63, wid = t >> 6;
    int i = blockIdx.x * 256 + t;
    int v = (i < N_NODES) ? cnt[i] + 1 : 0;
    int sc = v;
#pragma unroll
    for (int off = 1; off < 64; off <<= 1) {
        int y = __shfl_up(sc, off, 64);
        if (lane >= off) sc += y;
    }
    __shared__ int wsum[4], wexcl[4];
    if (lane == 63) wsum[wid] = sc;
    __syncthreads();
    if (t == 0) {
        int r = 0;
#pragma unroll
        for (int w = 0; w < 4; ++w) { wexcl[w] = r; r += wsum[w]; }
    }
    __syncthreads();
    if (i < N_NODES) {
        int excl = bpre[blockIdx.x] + wexcl[wid] + sc - v;
        rowptr[i] = excl;
        cursor[i] = excl;
        dis[i] = rsqrtf((float)(deg[i] + 1));
    }
}

__global__ void k_fill(const int* __restrict__ ei,
                       int* __restrict__ cursor, int* __restrict__ srcl) {
    int tid = blockIdx.x * 256 + threadIdx.x;
    if (tid < N_EDGES / 4) {
        int4 r = *(const int4*)&ei[tid * 4];
        int4 c = *(const int4*)&ei[N_EDGES + tid * 4];
        int p;
        p = atomicAdd(&cursor[c.x], 1); srcl[p] = r.x;
        p = atomicAdd(&cursor[c.y], 1); srcl[p] = r.y;
        p = atomicAdd(&cursor[c.z], 1); srcl[p] = r.z;
        p = atomicAdd(&cursor[c.w], 1); srcl[p] = r.w;
    } else if (tid < N_EDGES / 4 + N_NODES / 4) {
        int n4 = (tid - N_EDGES / 4) * 4;
#pragma unroll
        for (int j = 0; j < 4; ++j) {
            int n = n4 + j;
            int p = atomicAdd(&cursor[n], 1);
            srcl[p] = n;                        // self loop
        }
    }
}

// both weight transposes in one dispatch: WT[n][k] = bf16(W[k][n])
__global__ void k_prep_w2(const float* __restrict__ W1, const float* __restrict__ W2,
                          u16* __restrict__ W1T, u16* __restrict__ W2T) {
    int tid = blockIdx.x * 256 + threadIdx.x;    // 16384
    const float* W = (tid < 8192) ? W1 : W2;
    u16* WT = (tid < 8192) ? W1T : W2T;
    int id = tid & 8191;
    int n = id >> 5, k8 = (id & 31) << 3;
    u16 tmp[8];
#pragma unroll
    for (int i = 0; i < 8; ++i) tmp[i] = (u16)f2bf(W[(size_t)(k8 + i) * 256 + n]);
    *(uint4*)&WT[(size_t)n * 256 + k8] = *(uint4*)tmp;
}

// ------------------------------------------------------------- MFMA GEMM
// out = dis[m] * ( A @ W + bias );  writes bf16 (W16) and/or fp8 (W8).
// BM=128, BN=256, BK=32, 256 thr = 2x2 waves, wave-tile 64x128.
// SPLIT: A = concat(x,feat) f32, converted to bf16 during staging.

template <bool SPLIT, bool W16, bool W8>
__global__ __launch_bounds__(256, 2) void k_gemm_mfma(
    const void* __restrict__ A0v, const float* __restrict__ A1,
    const u16* __restrict__ WT, const float* __restrict__ bias,
    const float* __restrict__ dis, u16* __restrict__ out16,
    u8* __restrict__ out8, int M) {
    __shared__ u16 As[128][LDK];
    __shared__ u16 Bs[256][LDK];
    const int t = threadIdx.x;
    const int m0 = blockIdx.x * 128;
    const int lane = t & 63, wave = t >> 6;
    const int wm = wave & 1, wn = wave >> 1;
    const int lr = lane & 15, kg = lane >> 4;

    f32x4 acc[4][8] = {};

    for (int k0 = 0; k0 < 256; k0 += 32) {
#pragma unroll
        for (int i = 0; i < 2; ++i) {
            int idx = i * 256 + t;
            int row = idx >> 2, kc = (idx & 3) << 3;
            int grow = m0 + row;
            uint4 pk = {0u, 0u, 0u, 0u};
            if (grow < M) {
                if (SPLIT) {
                    int k = k0 + kc;            // 8-aligned, never straddles 128
                    const float* src = (k < 128)
                        ? ((const float*)A0v + (size_t)grow * 128 + k)
                        : (A1 + (size_t)grow * 128 + (k - 128));
                    float4 f0 = *(const float4*)src;
                    float4 f1 = *(const float4*)(src + 4);
                    pk.x = f2bf(f0.x) | (f2bf(f0.y) << 16);
                    pk.y = f2bf(f0.z) | (f2bf(f0.w) << 16);
                    pk.z = f2bf(f1.x) | (f2bf(f1.y) << 16);
                    pk.w = f2bf(f1.z) | (f2bf(f1.w) << 16);
                } else {
                    pk = *(const uint4*)((const u16*)A0v +
                                         (size_t)grow * 256 + k0 + kc);
                }
            }
            *(uint4*)&As[row][kc] = pk;
        }
#pragma unroll
        for (int i = 0; i < 4; ++i) {
            int idx = i * 256 + t;
            int n = idx >> 2, kc = (idx & 3) << 3;
            *(uint4*)&Bs[n][kc] = *(const uint4*)&WT[(size_t)n * 256 + k0 + kc];
        }
        __syncthreads();
        short8 af[4], bf[8];
#pragma unroll
        for (int mi = 0; mi < 4; ++mi)
            af[mi] = *(const short8*)&As[wm * 64 + mi * 16 + lr][kg * 8];
#pragma unroll
        for (int ni = 0; ni < 8; ++ni)
            bf[ni] = *(const short8*)&Bs[wn * 128 + ni * 16 + lr][kg * 8];
#pragma unroll
        for (int mi = 0; mi < 4; ++mi)
#pragma unroll
            for (int ni = 0; ni < 8; ++ni)
                acc[mi][ni] = __builtin_amdgcn_mfma_f32_16x16x32_bf16(
                    af[mi], bf[ni], acc[mi][ni], 0, 0, 0);
        __syncthreads();
    }

    const int orow = m0 + wm * 64;
    const int ocol = wn * 128;
#pragma unroll
    for (int mi = 0; mi < 4; ++mi) {
#pragma unroll
        for (int r = 0; r < 4; ++r) {
            int row = orow + mi * 16 + kg * 4 + r;
            if (row >= M) continue;
            float d = dis[row];
#pragma unroll
            for (int ni = 0; ni < 8; ++ni) {
                int col = ocol + ni * 16 + lr;
                float v = d * (acc[mi][ni][r] + bias[col]);
                if (W16) out16[(size_t)row * 256 + col] = (u16)f2bf(v);
                if (W8)  out8[(size_t)row * 256 + col] = f2fp8(v);
            }
        }
    }
}

// ----------------------------------------------------------- CSR aggregation
// fp8 rows (256B = 2 cache lines/edge, halves the MSHR-bound line count).
// Wave per dst; half-wave covers the row with 8B/lane; 16 edges in flight
// per half-wave, branch-free via zero-row padding (index N_NODES).

static __device__ __forceinline__ void addf8(uint2 v, float* a) {
    auto f0 = __builtin_amdgcn_cvt_pk_f32_fp8((int)v.x, false);
    auto f1 = __builtin_amdgcn_cvt_pk_f32_fp8((int)v.x, true);
    auto f2 = __builtin_amdgcn_cvt_pk_f32_fp8((int)v.y, false);
    auto f3 = __builtin_amdgcn_cvt_pk_f32_fp8((int)v.y, true);
    a[0] += f0[0]; a[1] += f0[1]; a[2] += f1[0]; a[3] += f1[1];
    a[4] += f2[0]; a[5] += f2[1]; a[6] += f3[0]; a[7] += f3[1];
}

static __device__ __forceinline__ void gather_batch16_f8(
    const int* __restrict__ p, const u8* __restrict__ base, float* a) {
    int4 q0 = *(const int4*)p;              // ds_read_b128 broadcast
    int4 q1 = *(const int4*)(p + 4);
    int4 q2 = *(const int4*)(p + 8);
    int4 q3 = *(const int4*)(p + 12);
    uint2 v0  = *(const uint2*)(base + (size_t)q0.x * 256);
    uint2 v1  = *(const uint2*)(base + (size_t)q0.y * 256);
    uint2 v2  = *(const uint2*)(base + (size_t)q0.z * 256);
    uint2 v3  = *(const uint2*)(base + (size_t)q0.w * 256);
    uint2 v4  = *(const uint2*)(base + (size_t)q1.x * 256);
    uint2 v5  = *(const uint2*)(base + (size_t)q1.y * 256);
    uint2 v6  = *(const uint2*)(base + (size_t)q1.z * 256);
    uint2 v7  = *(const uint2*)(base + (size_t)q1.w * 256);
    uint2 v8  = *(const uint2*)(base + (size_t)q2.x * 256);
    uint2 v9  = *(const uint2*)(base + (size_t)q2.y * 256);
    uint2 v10 = *(const uint2*)(base + (size_t)q2.z * 256);
    uint2 v11 = *(const uint2*)(base + (size_t)q2.w * 256);
    uint2 v12 = *(const uint2*)(base + (size_t)q3.x * 256);
    uint2 v13 = *(const uint2*)(base + (size_t)q3.y * 256);
    uint2 v14 = *(const uint2*)(base + (size_t)q3.z * 256);
    uint2 v15 = *(const uint2*)(base + (size_t)q3.w * 256);
    addf8(v0, a);  addf8(v1, a);  addf8(v2, a);  addf8(v3, a);
    addf8(v4, a);  addf8(v5, a);  addf8(v6, a);  addf8(v7, a);
    addf8(v8, a);  addf8(v9, a);  addf8(v10, a); addf8(v11, a);
    addf8(v12, a); addf8(v13, a); addf8(v14, a); addf8(v15, a);
}

// agg1: h2(bf16) = relu(dis .* gather-sum(h1 fp8))
__global__ __launch_bounds__(256) void k_agg_f8(
    const int* __restrict__ rowptr, const int* __restrict__ rowend,
    const int* __restrict__ srcl, const u8* __restrict__ hs,
    const float* __restrict__ dis, u16* __restrict__ out) {
    __shared__ int idxb[4][64];
    int wave = threadIdx.x >> 6;
    int lane = threadIdx.x & 63;
    int half = lane >> 5;
    int c8 = lane & 31;                     // channel group (8 ch)
    int dst = blockIdx.x * 4 + wave;
    if (dst >= N_NODES) return;
    int s = rowptr[dst], e = rowend[dst];
    const u8* base = hs + c8 * 8;
    float a[8] = {0.f, 0.f, 0.f, 0.f, 0.f, 0.f, 0.f, 0.f};
    for (int k0 = s; k0 < e; k0 += 64) {
        int kk = k0 + lane;
        idxb[wave][lane] = (kk < e) ? __builtin_nontemporal_load(&srcl[kk])
                                    : N_NODES;           // zero row
        int nn = min(64, e - k0);
        for (int j = 0; j < nn; j += 32)
            gather_batch16_f8(&idxb[wave][j + half * 16], base, a);
    }
#pragma unroll
    for (int j = 0; j < 8; ++j) a[j] += __shfl_xor(a[j], 32, 64);
    if (half == 0) {
        float d = dis[dst];
        uint4 p;
        p.x = f2bf(fmaxf(a[0] * d, 0.f)) | (f2bf(fmaxf(a[1] * d, 0.f)) << 16);
        p.y = f2bf(fmaxf(a[2] * d, 0.f)) | (f2bf(fmaxf(a[3] * d, 0.f)) << 16);
        p.z = f2bf(fmaxf(a[4] * d, 0.f)) | (f2bf(fmaxf(a[5] * d, 0.f)) << 16);
        p.w = f2bf(fmaxf(a[6] * d, 0.f)) | (f2bf(fmaxf(a[7] * d, 0.f)) << 16);
        *(uint4*)&out[(size_t)dst * 256 + c8 * 8] = p;
    }
}

// agg2 + pool: fp8 gather, track per-channel packed (valbits,dst); exact
// value recovered later by k_fix from the bf16 h3. g >= 0 so float-bit
// ordering works under u64 max.

static __device__ __forceinline__ ull packmd(float v, int dstid) {
    return ((ull)__float_as_uint(v) << 32) | (unsigned)dstid;
}

__global__ __launch_bounds__(256) void k_agg_pool_f8(
    const int* __restrict__ rowptr, const int* __restrict__ rowend,
    const int* __restrict__ srcl, const u8* __restrict__ hs,
    const float* __restrict__ dis, ull* __restrict__ gpool) {
    __shared__ int idxb[4][64];
    __shared__ ull lm[4][256];
    int wave = threadIdx.x >> 6;
    int lane = threadIdx.x & 63;
    int half = lane >> 5;
    int c8 = lane & 31;
    const u8* base = hs + c8 * 8;
    float m[8] = {0.f, 0.f, 0.f, 0.f, 0.f, 0.f, 0.f, 0.f};
    int   ad[8] = {0, 0, 0, 0, 0, 0, 0, 0};
    for (int dst = blockIdx.x * 4 + wave; dst < N_NODES;
         dst += POOL_BLOCKS * 4) {
        int s = rowptr[dst], e = rowend[dst];
        float a[8] = {0.f, 0.f, 0.f, 0.f, 0.f, 0.f, 0.f, 0.f};
        for (int k0 = s; k0 < e; k0 += 64) {
            int kk = k0 + lane;
            idxb[wave][lane] = (kk < e) ? __builtin_nontemporal_load(&srcl[kk])
                                        : N_NODES;       // zero row
            int nn = min(64, e - k0);
            for (int j = 0; j < nn; j += 32)
                gather_batch16_f8(&idxb[wave][j + half * 16], base, a);
        }
        float d = dis[dst];
#pragma unroll
        for (int j = 0; j < 8; ++j) {
            float v = (a[j] + __shfl_xor(a[j], 32, 64)) * d;
            if (v > m[j]) { m[j] = v; ad[j] = dst; }
        }
    }
    if (half == 0) {
#pragma unroll
        for (int j = 0; j < 8; ++j) lm[wave][c8 * 8 + j] = packmd(m[j], ad[j]);
    }
    __syncthreads();
    int t = threadIdx.x;
    ull v = lm[0][t];
    v = (lm[1][t] > v) ? lm[1][t] : v;
    v = (lm[2][t] > v) ? lm[2][t] : v;
    v = (lm[3][t] > v) ? lm[3][t] : v;
    atomicMax(&gpool[t], v);
}

// exact repair: re-aggregate each channel's winning dst from bf16 h3
__global__ __launch_bounds__(256) void k_fix(
    const ull* __restrict__ gpool, const int* __restrict__ rowptr,
    const int* __restrict__ rowend, const int* __restrict__ srcl,
    const u16* __restrict__ h3, const float* __restrict__ dis,
    float* __restrict__ g) {
    int t = threadIdx.x;                    // channel
    int dst = (int)(unsigned)(gpool[t] & 0xffffffffull);
    int s = rowptr[dst], e = rowend[dst];
    float sum = 0.f;
    for (int k = s; k < e; ++k) {
        int src = srcl[k];
        sum += bflo((unsigned)h3[(size_t)src * 256 + t]);
    }
    g[t] = fmaxf(dis[dst] * sum, 0.f);
}

// --------------------------------------------------------------------- head

__global__ __launch_bounds__(128) void k_head(
    const float* __restrict__ g, const float* __restrict__ Wp,
    const float* __restrict__ bp, const float* __restrict__ Wq,
    const float* __restrict__ bq, float* __restrict__ out) {
    __shared__ float sg[NHID];
    __shared__ float red[128];
    int t = threadIdx.x;
    sg[t] = g[t];
    sg[t + 128] = g[t + 128];
    __syncthreads();

    float v = 0.0f;
    if (t < NRES_P1) {
        float acc = bp[t];
        for (int k = 0; k < NHID; ++k) acc = fmaf(sg[k], Wp[k * NRES_P1 + t], acc);
        out[t] = acc;
        v = acc;
    }
    red[t] = (t < NRES_P1) ? v : -1e30f;
    __syncthreads();
#pragma unroll
    for (int off = 64; off > 0; off >>= 1) {
        if (t < off) red[t] = fmaxf(red[t], red[t + off]);
        __syncthreads();
    }
    float mx = red[0];
    __syncthreads();
    float ex = (t < NRES_P1) ? expf(v - mx) : 0.0f;
    red[t] = ex;
    __syncthreads();
#pragma unroll
    for (int off = 64; off > 0; off >>= 1) {
        if (t < off) red[t] += red[t + off];
        __syncthreads();
    }
    float sum = red[0];
    if (t < NRES_P1) out[NRES_P1 + t] = ex / sum;

    if (t < 64) {
        float a = fmaf(sg[t], Wq[t], 0.f);
        a = fmaf(sg[t + 64],  Wq[t + 64],  a);
        a = fmaf(sg[t + 128], Wq[t + 128], a);
        a = fmaf(sg[t + 192], Wq[t + 192], a);
#pragma unroll
        for (int off = 32; off > 0; off >>= 1) a += __shfl_down(a, off, 64);
        if (t == 0) out[2 * NRES_P1] = a + bq[0];
    }
}

// -------------------------------------------------------------------- launch

static inline size_t align256(size_t x) { return (x + 255) & ~size_t(255); }

extern "C" void kernel_launch(void* const* d_in, const int* in_sizes, int n_in,
                              void* d_out, int out_size, void* d_ws,
                              size_t ws_size, hipStream_t stream) {
    (void)in_sizes; (void)n_in; (void)out_size; (void)ws_size;
    const float* x    = (const float*)d_in[0];
    const float* feat = (const float*)d_in[1];
    const int*   ei   = (const int*)d_in[2];   // int32 (harness-converted)
    const float* W1   = (const float*)d_in[3];
    const float* b1   = (const float*)d_in[4];
    const float* W2   = (const float*)d_in[5];
    const float* b2   = (const float*)d_in[6];
    const float* Wp   = (const float*)d_in[7];
    const float* bp   = (const float*)d_in[8];
    const float* Wq   = (const float*)d_in[9];
    const float* bq   = (const float*)d_in[10];
    float* out = (float*)d_out;

    char* ws = (char*)d_ws;
    size_t off = 0;
    auto alloc = [&](size_t bytes) {
        void* p = ws + off;
        off = align256(off + bytes);
        return p;
    };
    int*   deg    = (int*)alloc(4ull * N_NODES);
    int*   indeg  = (int*)alloc(4ull * N_NODES);
    int*   rowptr = (int*)alloc(4ull * (N_NODES + 1));
    int*   cursor = (int*)alloc(4ull * (N_NODES + 1));
    int*   srcl   = (int*)alloc(4ull * (N_EDGES + N_NODES));
    int*   bsum   = (int*)alloc(4ull * NB_SCAN);
    int*   bpre   = (int*)alloc(4ull * NB_SCAN);
    float* dis    = (float*)alloc(4ull * N_NODES);
    float* g      = (float*)alloc(4ull * NHID);
    ull*   gpool  = (ull*)alloc(8ull * NHID);
    u16*   W1T    = (u16*)alloc(2ull * 256 * 256);
    u16*   W2T    = (u16*)alloc(2ull * 256 * 256);
    u8*    buf1f8 = (u8*)alloc(1ull * (N_NODES + 1) * 256);  // h1 fp8 (+zero)
    u16*   buf2   = (u16*)alloc(2ull * N_NODES * 256);       // h2 bf16
    u16*   buf3   = (u16*)alloc(2ull * N_NODES * 256);       // h3 bf16 (exact)
    u8*    buf3f8 = (u8*)alloc(1ull * (N_NODES + 1) * 256);  // h3 fp8 (+zero)

    hipMemsetAsync(deg,   0, 4ull * N_NODES, stream);
    hipMemsetAsync(indeg, 0, 4ull * N_NODES, stream);
    hipMemsetAsync(gpool, 0, 8ull * NHID,    stream);
    // zero rows (gather padding targets)
    hipMemsetAsync(buf1f8 + (size_t)N_NODES * 256, 0, 256, stream);
    hipMemsetAsync(buf3f8 + (size_t)N_NODES * 256, 0, 256, stream);

    k_prep_w2<<<64, 256, 0, stream>>>(W1, W2, W1T, W2T);
    k_count<<<(N_EDGES / 4 + 255) / 256, 256, 0, stream>>>(ei, deg, indeg);
    k_scan1<<<NB_SCAN, 256, 0, stream>>>(indeg, bsum);
    k_scan2<<<1, 256, 0, stream>>>(bsum, bpre);
    k_scan3<<<NB_SCAN, 256, 0, stream>>>(indeg, bpre, deg, rowptr, cursor, dis);
    k_fill<<<(N_EDGES / 4 + N_NODES / 4 + 255) / 256, 256, 0, stream>>>(
        ei, cursor, srcl);

    const int gblocks = (N_NODES + 127) / 128;
    // conv1 linear -> h1 fp8
    k_gemm_mfma<true, false, true><<<gblocks, 256, 0, stream>>>(
        x, feat, W1T, b1, dis, nullptr, buf1f8, N_NODES);
    // agg1: h2 = bf16(relu(dis .* gather-sum(h1 fp8)))
    k_agg_f8<<<(N_NODES + 3) / 4, 256, 0, stream>>>(rowptr, cursor, srcl,
                                                    buf1f8, dis, buf2);
    // conv2 linear -> h3 bf16 (exact) + fp8 (gather)
    k_gemm_mfma<false, true, true><<<gblocks, 256, 0, stream>>>(
        buf2, nullptr, W2T, b2, dis, buf3, buf3f8, N_NODES);
    // agg2 + pool: approx max + argmax via fp8
    k_agg_pool_f8<<<POOL_BLOCKS, 256, 0, stream>>>(rowptr, cursor, srcl,
                                                   buf3f8, dis, gpool);
    // exact repair of the winning dst per channel
    k_fix<<<1, 256, 0, stream>>>(gpool, rowptr, cursor, srcl, buf3, dis, g);

    k_head<<<1, 128, 0, stream>>>(g, Wp, bp, Wq, bq, out);
}

// Round 10
// 262.602 us; speedup vs baseline: 1.2825x; 1.2255x over previous
//
#include <hip/hip_runtime.h>

#define N_NODES 50000
#define N_EDGES 800000
#define NHID    256
#define NRES_P1 101

#define NBUCK   196            // node buckets (node >> 8), 50000/256 -> 196
#define EPB     3125           // edges per scatter block (256 blocks exactly)
#define BCAP    6144           // per-bucket staging cap (mean 4096+256, +30 sigma)
#define POOL_BLOCKS 512        // fused agg2+pool grid (u64 atomics capped)
#define LDK     40             // LDS k-stride (u16): 80B, 16B-aligned

typedef unsigned short u16;
typedef unsigned char  u8;
typedef unsigned long long ull;
typedef __attribute__((ext_vector_type(8))) short short8;   // 8 bf16
typedef __attribute__((ext_vector_type(4))) float f32x4;

static __device__ __forceinline__ unsigned f2bf(float f) {  // RNE -> low 16
    unsigned u = __float_as_uint(f);
    return (u + 0x7FFF + ((u >> 16) & 1)) >> 16;
}
static __device__ __forceinline__ float bflo(unsigned p) {
    return __uint_as_float(p << 16);
}
static __device__ __forceinline__ u8 f2fp8(float f) {       // HW e4m3 (OCP)
    return (u8)(__builtin_amdgcn_cvt_pk_fp8_f32(f, f, 0, false) & 0xff);
}

// --------------------------------------------- graph prep: bucket sort (no
// global atomics — LDS atomics + dense writes only)

// pass A: per-block bucket histograms of c>>8 and r>>8
__global__ __launch_bounds__(256) void k_bcount(
    const int* __restrict__ ei, int* __restrict__ pC, int* __restrict__ pR) {
    __shared__ int cC[NBUCK], cR[NBUCK];
    int b = blockIdx.x, t = threadIdx.x;
    if (t < NBUCK) { cC[t] = 0; cR[t] = 0; }
    __syncthreads();
    int base = b * EPB;
    for (int i = t; i < EPB; i += 256) {
        int r = ei[base + i];
        int c = ei[N_EDGES + base + i];
        atomicAdd(&cR[r >> 8], 1);
        atomicAdd(&cC[c >> 8], 1);
    }
    __syncthreads();
    if (t < NBUCK) { pC[b * NBUCK + t] = cC[t]; pR[b * NBUCK + t] = cR[t]; }
}

// pass A2: per-bucket exclusive block offsets + bucket edge starts
__global__ __launch_bounds__(256) void k_bscan(
    const int* __restrict__ pC, const int* __restrict__ pR,
    int* __restrict__ offC, int* __restrict__ offR,
    int* __restrict__ estC, int* __restrict__ estR) {
    __shared__ int totC[NBUCK], totR[NBUCK];
    int t = threadIdx.x;
    if (t < NBUCK) {
        int runC = 0, runR = 0;
        for (int b = 0; b < 256; b += 8) {
            int vc[8], vr[8];
#pragma unroll
            for (int j = 0; j < 8; ++j) {           // 16 loads in flight
                vc[j] = pC[(b + j) * NBUCK + t];
                vr[j] = pR[(b + j) * NBUCK + t];
            }
#pragma unroll
            for (int j = 0; j < 8; ++j) {
                offC[t * 256 + b + j] = runC; runC += vc[j];
                offR[t * 256 + b + j] = runR; runR += vr[j];
            }
        }
        totC[t] = runC; totR[t] = runR;
    }
    __syncthreads();
    if (t == 0) {
        int rc = 0, rr = 0;
        for (int k = 0; k < NBUCK; ++k) {
            estC[k] = rc; rc += totC[k];
            estR[k] = rr; rr += totR[k];
        }
        estC[NBUCK] = rc; estR[NBUCK] = rr;
    }
}

// pass B: scatter edges into bucket-sorted arrays via LDS cursors
__global__ __launch_bounds__(256) void k_bscatter(
    const int* __restrict__ ei, const int* __restrict__ offC,
    const int* __restrict__ offR, const int* __restrict__ estC,
    const int* __restrict__ estR, unsigned* __restrict__ sortC,
    u16* __restrict__ sortR) {
    __shared__ int curC[NBUCK], curR[NBUCK];
    int b = blockIdx.x, t = threadIdx.x;
    if (t < NBUCK) {
        curC[t] = estC[t] + offC[t * 256 + b];
        curR[t] = estR[t] + offR[t * 256 + b];
    }
    __syncthreads();
    int base = b * EPB;
    for (int i = t; i < EPB; i += 256) {
        int r = ei[base + i];
        int c = ei[N_EDGES + base + i];
        int pc = atomicAdd(&curC[c >> 8], 1);
        sortC[pc] = ((unsigned)(c & 255) << 16) | (unsigned)r;  // r < 65536
        int pr = atomicAdd(&curR[r >> 8], 1);
        sortR[pr] = (u16)(r & 255);
    }
}

// pass C: per-bucket exact CSR (rowptr/rowend/srcl, self-loop at row end)
__global__ __launch_bounds__(256) void k_bcsr(
    const unsigned* __restrict__ sortC, const int* __restrict__ estC,
    int* __restrict__ rowptr, int* __restrict__ rowend,
    int* __restrict__ srcl) {
    __shared__ int hist[256], cur[256], excl[256];
    __shared__ int wsum[4], woff[4];
    __shared__ unsigned stg[BCAP];
    int k = blockIdx.x, t = threadIdx.x;
    int lane = t & 63, wid = t >> 6;
    int nloc = min(256, N_NODES - k * 256);
    int es = estC[k], ee = estC[k + 1];
    int ecnt = ee - es;
    int fs = es + k * 256;                  // + self slots of prior buckets
    hist[t] = 0; cur[t] = 0;
    __syncthreads();
    for (int i = t; i < ecnt; i += 256)
        atomicAdd(&hist[sortC[es + i] >> 16], 1);
    __syncthreads();
    // exclusive scan of row sizes S[t] = hist[t] + (t<nloc)
    int sv = hist[t] + (t < nloc ? 1 : 0);
    int sc = sv;
#pragma unroll
    for (int off = 1; off < 64; off <<= 1) {
        int y = __shfl_up(sc, off, 64);
        if (lane >= off) sc += y;
    }
    if (lane == 63) wsum[wid] = sc;
    __syncthreads();
    if (t == 0) {
        int r = 0;
#pragma unroll
        for (int w = 0; w < 4; ++w) { woff[w] = r; r += wsum[w]; }
    }
    __syncthreads();
    int ex = woff[wid] + sc - sv;
    excl[t] = ex;
    if (t < nloc) {
        rowptr[k * 256 + t] = fs + ex;
        rowend[k * 256 + t] = fs + ex + hist[t] + 1;
    }
    __syncthreads();
    int tot = ecnt + nloc;
    if (tot <= BCAP) {
        for (int i = t; i < ecnt; i += 256) {
            unsigned v = sortC[es + i];
            int j = v >> 16;
            int p = excl[j] + atomicAdd(&cur[j], 1);
            stg[p] = v & 0xffffu;
        }
        if (t < nloc) stg[excl[t] + hist[t]] = (unsigned)(k * 256 + t);
        __syncthreads();
        for (int i = t; i < tot; i += 256) srcl[fs + i] = (int)stg[i];
    } else {                                 // safety fallback (never expected)
        for (int i = t; i < ecnt; i += 256) {
            unsigned v = sortC[es + i];
            int j = v >> 16;
            int p = excl[j] + atomicAdd(&cur[j], 1);
            srcl[fs + p] = (int)(v & 0xffffu);
        }
        if (t < nloc) srcl[fs + excl[t] + hist[t]] = k * 256 + t;
    }
}

// pass C': per-bucket exact out-degree histogram -> dis
__global__ __launch_bounds__(256) void k_deg(
    const u16* __restrict__ sortR, const int* __restrict__ estR,
    float* __restrict__ dis) {
    __shared__ int hist[256];
    int k = blockIdx.x, t = threadIdx.x;
    int nloc = min(256, N_NODES - k * 256);
    int es = estR[k], ecnt = estR[k + 1] - es;
    hist[t] = 0;
    __syncthreads();
    for (int i = t; i < ecnt; i += 256)
        atomicAdd(&hist[(int)sortR[es + i]], 1);
    __syncthreads();
    if (t < nloc) dis[k * 256 + t] = rsqrtf((float)(hist[t] + 1));
}

// both weight transposes in one dispatch: WT[n][k] = bf16(W[k][n])
__global__ void k_prep_w2(const float* __restrict__ W1, const float* __restrict__ W2,
                          u16* __restrict__ W1T, u16* __restrict__ W2T) {
    int tid = blockIdx.x * 256 + threadIdx.x;    // 16384
    const float* W = (tid < 8192) ? W1 : W2;
    u16* WT = (tid < 8192) ? W1T : W2T;
    int id = tid & 8191;
    int n = id >> 5, k8 = (id & 31) << 3;
    u16 tmp[8];
#pragma unroll
    for (int i = 0; i < 8; ++i) tmp[i] = (u16)f2bf(W[(size_t)(k8 + i) * 256 + n]);
    *(uint4*)&WT[(size_t)n * 256 + k8] = *(uint4*)tmp;
}

// ------------------------------------------------------------- MFMA GEMM
// out = dis[m] * ( A @ W + bias );  writes bf16 (W16) and/or fp8 (W8).

template <bool SPLIT, bool W16, bool W8>
__global__ __launch_bounds__(256, 2) void k_gemm_mfma(
    const void* __restrict__ A0v, const float* __restrict__ A1,
    const u16* __restrict__ WT, const float* __restrict__ bias,
    const float* __restrict__ dis, u16* __restrict__ out16,
    u8* __restrict__ out8, int M) {
    __shared__ u16 As[128][LDK];
    __shared__ u16 Bs[256][LDK];
    const int t = threadIdx.x;
    const int m0 = blockIdx.x * 128;
    const int lane = t & 63, wave = t >> 6;
    const int wm = wave & 1, wn = wave >> 1;
    const int lr = lane & 15, kg = lane >> 4;

    f32x4 acc[4][8] = {};

    for (int k0 = 0; k0 < 256; k0 += 32) {
#pragma unroll
        for (int i = 0; i < 2; ++i) {
            int idx = i * 256 + t;
            int row = idx >> 2, kc = (idx & 3) << 3;
            int grow = m0 + row;
            uint4 pk = {0u, 0u, 0u, 0u};
            if (grow < M) {
                if (SPLIT) {
                    int k = k0 + kc;            // 8-aligned, never straddles 128
                    const float* src = (k < 128)
                        ? ((const float*)A0v + (size_t)grow * 128 + k)
                        : (A1 + (size_t)grow * 128 + (k - 128));
                    float4 f0 = *(const float4*)src;
                    float4 f1 = *(const float4*)(src + 4);
                    pk.x = f2bf(f0.x) | (f2bf(f0.y) << 16);
                    pk.y = f2bf(f0.z) | (f2bf(f0.w) << 16);
                    pk.z = f2bf(f1.x) | (f2bf(f1.y) << 16);
                    pk.w = f2bf(f1.z) | (f2bf(f1.w) << 16);
                } else {
                    pk = *(const uint4*)((const u16*)A0v +
                                         (size_t)grow * 256 + k0 + kc);
                }
            }
            *(uint4*)&As[row][kc] = pk;
        }
#pragma unroll
        for (int i = 0; i < 4; ++i) {
            int idx = i * 256 + t;
            int n = idx >> 2, kc = (idx & 3) << 3;
            *(uint4*)&Bs[n][kc] = *(const uint4*)&WT[(size_t)n * 256 + k0 + kc];
        }
        __syncthreads();
        short8 af[4], bf[8];
#pragma unroll
        for (int mi = 0; mi < 4; ++mi)
            af[mi] = *(const short8*)&As[wm * 64 + mi * 16 + lr][kg * 8];
#pragma unroll
        for (int ni = 0; ni < 8; ++ni)
            bf[ni] = *(const short8*)&Bs[wn * 128 + ni * 16 + lr][kg * 8];
#pragma unroll
        for (int mi = 0; mi < 4; ++mi)
#pragma unroll
            for (int ni = 0; ni < 8; ++ni)
                acc[mi][ni] = __builtin_amdgcn_mfma_f32_16x16x32_bf16(
                    af[mi], bf[ni], acc[mi][ni], 0, 0, 0);
        __syncthreads();
    }

    const int orow = m0 + wm * 64;
    const int ocol = wn * 128;
#pragma unroll
    for (int mi = 0; mi < 4; ++mi) {
#pragma unroll
        for (int r = 0; r < 4; ++r) {
            int row = orow + mi * 16 + kg * 4 + r;
            if (row >= M) continue;
            float d = dis[row];
#pragma unroll
            for (int ni = 0; ni < 8; ++ni) {
                int col = ocol + ni * 16 + lr;
                float v = d * (acc[mi][ni][r] + bias[col]);
                if (W16) out16[(size_t)row * 256 + col] = (u16)f2bf(v);
                if (W8)  out8[(size_t)row * 256 + col] = f2fp8(v);
            }
        }
    }
}

// ----------------------------------------------------------- CSR aggregation
// fp8 rows (256B = 2 cache lines/edge). Wave per dst; half-wave covers the
// row with 8B/lane; 16 edges in flight per half-wave, branch-free via
// zero-row padding (index N_NODES).

static __device__ __forceinline__ void addf8(uint2 v, float* a) {
    auto f0 = __builtin_amdgcn_cvt_pk_f32_fp8((int)v.x, false);
    auto f1 = __builtin_amdgcn_cvt_pk_f32_fp8((int)v.x, true);
    auto f2 = __builtin_amdgcn_cvt_pk_f32_fp8((int)v.y, false);
    auto f3 = __builtin_amdgcn_cvt_pk_f32_fp8((int)v.y, true);
    a[0] += f0[0]; a[1] += f0[1]; a[2] += f1[0]; a[3] += f1[1];
    a[4] += f2[0]; a[5] += f2[1]; a[6] += f3[0]; a[7] += f3[1];
}

static __device__ __forceinline__ void gather_batch16_f8(
    const int* __restrict__ p, const u8* __restrict__ base, float* a) {
    int4 q0 = *(const int4*)p;              // ds_read_b128 broadcast
    int4 q1 = *(const int4*)(p + 4);
    int4 q2 = *(const int4*)(p + 8);
    int4 q3 = *(const int4*)(p + 12);
    uint2 v0  = *(const uint2*)(base + (size_t)q0.x * 256);
    uint2 v1  = *(const uint2*)(base + (size_t)q0.y * 256);
    uint2 v2  = *(const uint2*)(base + (size_t)q0.z * 256);
    uint2 v3  = *(const uint2*)(base + (size_t)q0.w * 256);
    uint2 v4  = *(const uint2*)(base + (size_t)q1.x * 256);
    uint2 v5  = *(const uint2*)(base + (size_t)q1.y * 256);
    uint2 v6  = *(const uint2*)(base + (size_t)q1.z * 256);
    uint2 v7  = *(const uint2*)(base + (size_t)q1.w * 256);
    uint2 v8  = *(const uint2*)(base + (size_t)q2.x * 256);
    uint2 v9  = *(const uint2*)(base + (size_t)q2.y * 256);
    uint2 v10 = *(const uint2*)(base + (size_t)q2.z * 256);
    uint2 v11 = *(const uint2*)(base + (size_t)q2.w * 256);
    uint2 v12 = *(const uint2*)(base + (size_t)q3.x * 256);
    uint2 v13 = *(const uint2*)(base + (size_t)q3.y * 256);
    uint2 v14 = *(const uint2*)(base + (size_t)q3.z * 256);
    uint2 v15 = *(const uint2*)(base + (size_t)q3.w * 256);
    addf8(v0, a);  addf8(v1, a);  addf8(v2, a);  addf8(v3, a);
    addf8(v4, a);  addf8(v5, a);  addf8(v6, a);  addf8(v7, a);
    addf8(v8, a);  addf8(v9, a);  addf8(v10, a); addf8(v11, a);
    addf8(v12, a); addf8(v13, a); addf8(v14, a); addf8(v15, a);
}

// agg1: h2(bf16) = relu(dis .* gather-sum(h1 fp8))
__global__ __launch_bounds__(256) void k_agg_f8(
    const int* __restrict__ rowptr, const int* __restrict__ rowend,
    const int* __restrict__ srcl, const u8* __restrict__ hs,
    const float* __restrict__ dis, u16* __restrict__ out) {
    __shared__ int idxb[4][64];
    int wave = threadIdx.x >> 6;
    int lane = threadIdx.x & 63;
    int half = lane >> 5;
    int c8 = lane & 31;                     // channel group (8 ch)
    int dst = blockIdx.x * 4 + wave;
    if (dst >= N_NODES) return;
    int s = rowptr[dst], e = rowend[dst];
    const u8* base = hs + c8 * 8;
    float a[8] = {0.f, 0.f, 0.f, 0.f, 0.f, 0.f, 0.f, 0.f};
    for (int k0 = s; k0 < e; k0 += 64) {
        int kk = k0 + lane;
        idxb[wave][lane] = (kk < e) ? __builtin_nontemporal_load(&srcl[kk])
                                    : N_NODES;           // zero row
        int nn = min(64, e - k0);
        for (int j = 0; j < nn; j += 32)
            gather_batch16_f8(&idxb[wave][j + half * 16], base, a);
    }
#pragma unroll
    for (int j = 0; j < 8; ++j) a[j] += __shfl_xor(a[j], 32, 64);
    if (half == 0) {
        float d = dis[dst];
        uint4 p;
        p.x = f2bf(fmaxf(a[0] * d, 0.f)) | (f2bf(fmaxf(a[1] * d, 0.f)) << 16);
        p.y = f2bf(fmaxf(a[2] * d, 0.f)) | (f2bf(fmaxf(a[3] * d, 0.f)) << 16);
        p.z = f2bf(fmaxf(a[4] * d, 0.f)) | (f2bf(fmaxf(a[5] * d, 0.f)) << 16);
        p.w = f2bf(fmaxf(a[6] * d, 0.f)) | (f2bf(fmaxf(a[7] * d, 0.f)) << 16);
        *(uint4*)&out[(size_t)dst * 256 + c8 * 8] = p;
    }
}

// agg2 + pool: fp8 gather, track per-channel packed (valbits,dst); exact
// value recovered by k_fix from bf16 h3. Values >= 0 so float-bit order ok.

static __device__ __forceinline__ ull packmd(float v, int dstid) {
    return ((ull)__float_as_uint(v) << 32) | (unsigned)dstid;
}

__global__ __launch_bounds__(256) void k_agg_pool_f8(
    const int* __restrict__ rowptr, const int* __restrict__ rowend,
    const int* __restrict__ srcl, const u8* __restrict__ hs,
    const float* __restrict__ dis, ull* __restrict__ gpool) {
    __shared__ int idxb[4][64];
    __shared__ ull lm[4][256];
    int wave = threadIdx.x >> 6;
    int lane = threadIdx.x & 63;
    int half = lane >> 5;
    int c8 = lane & 31;
    const u8* base = hs + c8 * 8;
    float m[8] = {0.f, 0.f, 0.f, 0.f, 0.f, 0.f, 0.f, 0.f};
    int   ad[8] = {0, 0, 0, 0, 0, 0, 0, 0};
    for (int dst = blockIdx.x * 4 + wave; dst < N_NODES;
         dst += POOL_BLOCKS * 4) {
        int s = rowptr[dst], e = rowend[dst];
        float a[8] = {0.f, 0.f, 0.f, 0.f, 0.f, 0.f, 0.f, 0.f};
        for (int k0 = s; k0 < e; k0 += 64) {
            int kk = k0 + lane;
            idxb[wave][lane] = (kk < e) ? __builtin_nontemporal_load(&srcl[kk])
                                        : N_NODES;       // zero row
            int nn = min(64, e - k0);
            for (int j = 0; j < nn; j += 32)
                gather_batch16_f8(&idxb[wave][j + half * 16], base, a);
        }
        float d = dis[dst];
#pragma unroll
        for (int j = 0; j < 8; ++j) {
            float v = (a[j] + __shfl_xor(a[j], 32, 64)) * d;
            if (v > m[j]) { m[j] = v; ad[j] = dst; }
        }
    }
    if (half == 0) {
#pragma unroll
        for (int j = 0; j < 8; ++j) lm[wave][c8 * 8 + j] = packmd(m[j], ad[j]);
    }
    __syncthreads();
    int t = threadIdx.x;
    ull v = lm[0][t];
    v = (lm[1][t] > v) ? lm[1][t] : v;
    v = (lm[2][t] > v) ? lm[2][t] : v;
    v = (lm[3][t] > v) ? lm[3][t] : v;
    atomicMax(&gpool[t], v);
}

// exact repair: re-aggregate each channel's winning dst from bf16 h3
__global__ __launch_bounds__(256) void k_fix(
    const ull* __restrict__ gpool, const int* __restrict__ rowptr,
    const int* __restrict__ rowend, const int* __restrict__ srcl,
    const u16* __restrict__ h3, const float* __restrict__ dis,
    float* __restrict__ g) {
    int t = threadIdx.x;                    // channel
    int dst = (int)(unsigned)(gpool[t] & 0xffffffffull);
    int s = rowptr[dst], e = rowend[dst];
    float sum = 0.f;
    for (int k = s; k < e; ++k) {
        int src = srcl[k];
        sum += bflo((unsigned)h3[(size_t)src * 256 + t]);
    }
    g[t] = fmaxf(dis[dst] * sum, 0.f);
}

// --------------------------------------------------------------------- head

__global__ __launch_bounds__(128) void k_head(
    const float* __restrict__ g, const float* __restrict__ Wp,
    const float* __restrict__ bp, const float* __restrict__ Wq,
    const float* __restrict__ bq, float* __restrict__ out) {
    __shared__ float sg[NHID];
    __shared__ float red[128];
    int t = threadIdx.x;
    sg[t] = g[t];
    sg[t + 128] = g[t + 128];
    __syncthreads();

    float v = 0.0f;
    if (t < NRES_P1) {
        float acc = bp[t];
        for (int k = 0; k < NHID; ++k) acc = fmaf(sg[k], Wp[k * NRES_P1 + t], acc);
        out[t] = acc;
        v = acc;
    }
    red[t] = (t < NRES_P1) ? v : -1e30f;
    __syncthreads();
#pragma unroll
    for (int off = 64; off > 0; off >>= 1) {
        if (t < off) red[t] = fmaxf(red[t], red[t + off]);
        __syncthreads();
    }
    float mx = red[0];
    __syncthreads();
    float ex = (t < NRES_P1) ? expf(v - mx) : 0.0f;
    red[t] = ex;
    __syncthreads();
#pragma unroll
    for (int off = 64; off > 0; off >>= 1) {
        if (t < off) red[t] += red[t + off];
        __syncthreads();
    }
    float sum = red[0];
    if (t < NRES_P1) out[NRES_P1 + t] = ex / sum;

    if (t < 64) {
        float a = fmaf(sg[t], Wq[t], 0.f);
        a = fmaf(sg[t + 64],  Wq[t + 64],  a);
        a = fmaf(sg[t + 128], Wq[t + 128], a);
        a = fmaf(sg[t + 192], Wq[t + 192], a);
#pragma unroll
        for (int off = 32; off > 0; off >>= 1) a += __shfl_down(a, off, 64);
        if (t == 0) out[2 * NRES_P1] = a + bq[0];
    }
}

// -------------------------------------------------------------------- launch

static inline size_t align256(size_t x) { return (x + 255) & ~size_t(255); }

extern "C" void kernel_launch(void* const* d_in, const int* in_sizes, int n_in,
                              void* d_out, int out_size, void* d_ws,
                              size_t ws_size, hipStream_t stream) {
    (void)in_sizes; (void)n_in; (void)out_size; (void)ws_size;
    const float* x    = (const float*)d_in[0];
    const float* feat = (const float*)d_in[1];
    const int*   ei   = (const int*)d_in[2];   // int32 (harness-converted)
    const float* W1   = (const float*)d_in[3];
    const float* b1   = (const float*)d_in[4];
    const float* W2   = (const float*)d_in[5];
    const float* b2   = (const float*)d_in[6];
    const float* Wp   = (const float*)d_in[7];
    const float* bp   = (const float*)d_in[8];
    const float* Wq   = (const float*)d_in[9];
    const float* bq   = (const float*)d_in[10];
    float* out = (float*)d_out;

    char* ws = (char*)d_ws;
    size_t off = 0;
    auto alloc = [&](size_t bytes) {
        void* p = ws + off;
        off = align256(off + bytes);
        return p;
    };
    int*   rowptr = (int*)alloc(4ull * N_NODES);
    int*   rowend = (int*)alloc(4ull * N_NODES);
    int*   srcl   = (int*)alloc(4ull * (N_EDGES + N_NODES));
    int*   estC   = (int*)alloc(4ull * (NBUCK + 1));
    int*   estR   = (int*)alloc(4ull * (NBUCK + 1));
    float* dis    = (float*)alloc(4ull * N_NODES);
    float* g      = (float*)alloc(4ull * NHID);
    ull*   gpool  = (ull*)alloc(8ull * NHID);
    u16*   W1T    = (u16*)alloc(2ull * 256 * 256);
    u16*   W2T    = (u16*)alloc(2ull * 256 * 256);
    u8*    buf1f8 = (u8*)alloc(1ull * (N_NODES + 1) * 256);  // h1 fp8 (+zero)
    u16*   buf2   = (u16*)alloc(2ull * N_NODES * 256);       // h2 bf16
    u16*   buf3   = (u16*)alloc(2ull * N_NODES * 256);       // h3 bf16 (exact)
    u8*    buf3f8 = (u8*)alloc(1ull * (N_NODES + 1) * 256);  // h3 fp8 (+zero)

    // transient prep buffers aliased into buf2/buf3 (dead before h2/h3 exist)
    int*      pC    = (int*)buf2;                            // 256*196 ints
    int*      pR    = pC  + 256 * NBUCK;
    int*      offC  = pR  + 256 * NBUCK;
    int*      offR  = offC + 256 * NBUCK;
    unsigned* sortC = (unsigned*)buf3;                       // 800k u32
    u16*      sortR = (u16*)((char*)buf3 + 4ull * N_EDGES);  // 800k u16

    hipMemsetAsync(gpool, 0, 8ull * NHID, stream);
    // zero rows (gather padding targets)
    hipMemsetAsync(buf1f8 + (size_t)N_NODES * 256, 0, 256, stream);
    hipMemsetAsync(buf3f8 + (size_t)N_NODES * 256, 0, 256, stream);

    k_prep_w2<<<64, 256, 0, stream>>>(W1, W2, W1T, W2T);
    k_bcount<<<256, 256, 0, stream>>>(ei, pC, pR);
    k_bscan<<<1, 256, 0, stream>>>(pC, pR, offC, offR, estC, estR);
    k_bscatter<<<256, 256, 0, stream>>>(ei, offC, offR, estC, estR,
                                        sortC, sortR);
    k_bcsr<<<NBUCK, 256, 0, stream>>>(sortC, estC, rowptr, rowend, srcl);
    k_deg<<<NBUCK, 256, 0, stream>>>(sortR, estR, dis);

    const int gblocks = (N_NODES + 127) / 128;
    // conv1 linear -> h1 fp8
    k_gemm_mfma<true, false, true><<<gblocks, 256, 0, stream>>>(
        x, feat, W1T, b1, dis, nullptr, buf1f8, N_NODES);
    // agg1: h2 = bf16(relu(dis .* gather-sum(h1 fp8)))
    k_agg_f8<<<(N_NODES + 3) / 4, 256, 0, stream>>>(rowptr, rowend, srcl,
                                                    buf1f8, dis, buf2);
    // conv2 linear -> h3 bf16 (exact) + fp8 (gather)
    k_gemm_mfma<false, true, true><<<gblocks, 256, 0, stream>>>(
        buf2, nullptr, W2T, b2, dis, buf3, buf3f8, N_NODES);
    // agg2 + pool: approx max + argmax via fp8
    k_agg_pool_f8<<<POOL_BLOCKS, 256, 0, stream>>>(rowptr, rowend, srcl,
                                                   buf3f8, dis, gpool);
    // exact repair of the winning dst per channel
    k_fix<<<1, 256, 0, stream>>>(gpool, rowptr, rowend, srcl, buf3, dis, g);

    k_head<<<1, 128, 0, stream>>>(g, Wp, bp, Wq, bq, out);
}

// Round 11
// 260.690 us; speedup vs baseline: 1.2919x; 1.0073x over previous
//
#include <hip/hip_runtime.h>

#define N_NODES 50000
#define N_EDGES 800000
#define NHID    256
#define NRES_P1 101

#define NBUCK   196            // node buckets (node >> 8), 50000/256 -> 196
#define EPB     3125           // edges per scatter block (256 blocks exactly)
#define BCAP    6144           // per-bucket staging cap (mean 4096+256, +30 sigma)
#define POOL_BLOCKS 2048       // fused agg2+pool grid (8 blocks/CU -> full occ)
#define LDK     40             // LDS k-stride (u16): 80B, 16B-aligned

typedef unsigned short u16;
typedef unsigned char  u8;
typedef unsigned long long ull;
typedef __attribute__((ext_vector_type(8))) short short8;   // 8 bf16
typedef __attribute__((ext_vector_type(4))) float f32x4;

static __device__ __forceinline__ unsigned f2bf(float f) {  // RNE -> low 16
    unsigned u = __float_as_uint(f);
    return (u + 0x7FFF + ((u >> 16) & 1)) >> 16;
}
static __device__ __forceinline__ float bflo(unsigned p) {
    return __uint_as_float(p << 16);
}
static __device__ __forceinline__ u8 f2fp8(float f) {       // HW e4m3 (OCP)
    return (u8)(__builtin_amdgcn_cvt_pk_fp8_f32(f, f, 0, false) & 0xff);
}

// --------------------------------------------- graph prep: bucket sort (no
// global atomics — LDS atomics + dense writes only)

// pass A: per-block bucket histograms of c>>8 and r>>8
__global__ __launch_bounds__(256) void k_bcount(
    const int* __restrict__ ei, int* __restrict__ pC, int* __restrict__ pR) {
    __shared__ int cC[NBUCK], cR[NBUCK];
    int b = blockIdx.x, t = threadIdx.x;
    if (t < NBUCK) { cC[t] = 0; cR[t] = 0; }
    __syncthreads();
    int base = b * EPB;
    for (int i = t; i < EPB; i += 256) {
        int r = ei[base + i];
        int c = ei[N_EDGES + base + i];
        atomicAdd(&cR[r >> 8], 1);
        atomicAdd(&cC[c >> 8], 1);
    }
    __syncthreads();
    if (t < NBUCK) { pC[b * NBUCK + t] = cC[t]; pR[b * NBUCK + t] = cR[t]; }
}

// pass A2: per-bucket exclusive block offsets + bucket edge starts
__global__ __launch_bounds__(256) void k_bscan(
    const int* __restrict__ pC, const int* __restrict__ pR,
    int* __restrict__ offC, int* __restrict__ offR,
    int* __restrict__ estC, int* __restrict__ estR) {
    __shared__ int totC[NBUCK], totR[NBUCK];
    int t = threadIdx.x;
    if (t < NBUCK) {
        int runC = 0, runR = 0;
        for (int b = 0; b < 256; b += 8) {
            int vc[8], vr[8];
#pragma unroll
            for (int j = 0; j < 8; ++j) {           // 16 loads in flight
                vc[j] = pC[(b + j) * NBUCK + t];
                vr[j] = pR[(b + j) * NBUCK + t];
            }
#pragma unroll
            for (int j = 0; j < 8; ++j) {
                offC[t * 256 + b + j] = runC; runC += vc[j];
                offR[t * 256 + b + j] = runR; runR += vr[j];
            }
        }
        totC[t] = runC; totR[t] = runR;
    }
    __syncthreads();
    if (t == 0) {
        int rc = 0, rr = 0;
        for (int k = 0; k < NBUCK; ++k) {
            estC[k] = rc; rc += totC[k];
            estR[k] = rr; rr += totR[k];
        }
        estC[NBUCK] = rc; estR[NBUCK] = rr;
    }
}

// pass B: scatter edges into bucket-sorted arrays via LDS cursors
__global__ __launch_bounds__(256) void k_bscatter(
    const int* __restrict__ ei, const int* __restrict__ offC,
    const int* __restrict__ offR, const int* __restrict__ estC,
    const int* __restrict__ estR, unsigned* __restrict__ sortC,
    u16* __restrict__ sortR) {
    __shared__ int curC[NBUCK], curR[NBUCK];
    int b = blockIdx.x, t = threadIdx.x;
    if (t < NBUCK) {
        curC[t] = estC[t] + offC[t * 256 + b];
        curR[t] = estR[t] + offR[t * 256 + b];
    }
    __syncthreads();
    int base = b * EPB;
    for (int i = t; i < EPB; i += 256) {
        int r = ei[base + i];
        int c = ei[N_EDGES + base + i];
        int pc = atomicAdd(&curC[c >> 8], 1);
        sortC[pc] = ((unsigned)(c & 255) << 16) | (unsigned)r;  // r < 65536
        int pr = atomicAdd(&curR[r >> 8], 1);
        sortR[pr] = (u16)(r & 255);
    }
}

// pass C: per-bucket exact CSR (rowptr/rowend/srcl, self-loop at row end)
// + out-degree histogram -> dis (merged k_deg)
__global__ __launch_bounds__(256) void k_bcsr(
    const unsigned* __restrict__ sortC, const int* __restrict__ estC,
    const u16* __restrict__ sortR, const int* __restrict__ estR,
    int* __restrict__ rowptr, int* __restrict__ rowend,
    int* __restrict__ srcl, float* __restrict__ dis) {
    __shared__ int hist[256], cur[256], excl[256], hist2[256];
    __shared__ int wsum[4], woff[4];
    __shared__ unsigned stg[BCAP];
    int k = blockIdx.x, t = threadIdx.x;
    int lane = t & 63, wid = t >> 6;
    int nloc = min(256, N_NODES - k * 256);
    int es = estC[k], ee = estC[k + 1];
    int ecnt = ee - es;
    int fs = es + k * 256;                  // + self slots of prior buckets
    hist[t] = 0; cur[t] = 0; hist2[t] = 0;
    __syncthreads();
    for (int i = t; i < ecnt; i += 256)
        atomicAdd(&hist[sortC[es + i] >> 16], 1);
    {   // out-degree histogram (merged k_deg)
        int rs = estR[k], rcnt = estR[k + 1] - rs;
        for (int i = t; i < rcnt; i += 256)
            atomicAdd(&hist2[(int)sortR[rs + i]], 1);
    }
    __syncthreads();
    if (t < nloc) dis[k * 256 + t] = rsqrtf((float)(hist2[t] + 1));
    // exclusive scan of row sizes S[t] = hist[t] + (t<nloc)
    int sv = hist[t] + (t < nloc ? 1 : 0);
    int sc = sv;
#pragma unroll
    for (int off = 1; off < 64; off <<= 1) {
        int y = __shfl_up(sc, off, 64);
        if (lane >= off) sc += y;
    }
    if (lane == 63) wsum[wid] = sc;
    __syncthreads();
    if (t == 0) {
        int r = 0;
#pragma unroll
        for (int w = 0; w < 4; ++w) { woff[w] = r; r += wsum[w]; }
    }
    __syncthreads();
    int ex = woff[wid] + sc - sv;
    excl[t] = ex;
    if (t < nloc) {
        rowptr[k * 256 + t] = fs + ex;
        rowend[k * 256 + t] = fs + ex + hist[t] + 1;
    }
    __syncthreads();
    int tot = ecnt + nloc;
    if (tot <= BCAP) {
        for (int i = t; i < ecnt; i += 256) {
            unsigned v = sortC[es + i];
            int j = v >> 16;
            int p = excl[j] + atomicAdd(&cur[j], 1);
            stg[p] = v & 0xffffu;
        }
        if (t < nloc) stg[excl[t] + hist[t]] = (unsigned)(k * 256 + t);
        __syncthreads();
        for (int i = t; i < tot; i += 256) srcl[fs + i] = (int)stg[i];
    } else {                                 // safety fallback (never expected)
        for (int i = t; i < ecnt; i += 256) {
            unsigned v = sortC[es + i];
            int j = v >> 16;
            int p = excl[j] + atomicAdd(&cur[j], 1);
            srcl[fs + p] = (int)(v & 0xffffu);
        }
        if (t < nloc) srcl[fs + excl[t] + hist[t]] = k * 256 + t;
    }
}

// both weight transposes in one dispatch: WT[n][k] = bf16(W[k][n])
__global__ void k_prep_w2(const float* __restrict__ W1, const float* __restrict__ W2,
                          u16* __restrict__ W1T, u16* __restrict__ W2T) {
    int tid = blockIdx.x * 256 + threadIdx.x;    // 16384
    const float* W = (tid < 8192) ? W1 : W2;
    u16* WT = (tid < 8192) ? W1T : W2T;
    int id = tid & 8191;
    int n = id >> 5, k8 = (id & 31) << 3;
    u16 tmp[8];
#pragma unroll
    for (int i = 0; i < 8; ++i) tmp[i] = (u16)f2bf(W[(size_t)(k8 + i) * 256 + n]);
    *(uint4*)&WT[(size_t)n * 256 + k8] = *(uint4*)tmp;
}

// ------------------------------------------------------------- MFMA GEMM
// out = dis[m] * ( A @ W + bias );  writes bf16 (W16) and/or fp8 (W8).

template <bool SPLIT, bool W16, bool W8>
__global__ __launch_bounds__(256, 2) void k_gemm_mfma(
    const void* __restrict__ A0v, const float* __restrict__ A1,
    const u16* __restrict__ WT, const float* __restrict__ bias,
    const float* __restrict__ dis, u16* __restrict__ out16,
    u8* __restrict__ out8, int M) {
    __shared__ u16 As[128][LDK];
    __shared__ u16 Bs[256][LDK];
    const int t = threadIdx.x;
    const int m0 = blockIdx.x * 128;
    const int lane = t & 63, wave = t >> 6;
    const int wm = wave & 1, wn = wave >> 1;
    const int lr = lane & 15, kg = lane >> 4;

    f32x4 acc[4][8] = {};

    for (int k0 = 0; k0 < 256; k0 += 32) {
#pragma unroll
        for (int i = 0; i < 2; ++i) {
            int idx = i * 256 + t;
            int row = idx >> 2, kc = (idx & 3) << 3;
            int grow = m0 + row;
            uint4 pk = {0u, 0u, 0u, 0u};
            if (grow < M) {
                if (SPLIT) {
                    int k = k0 + kc;            // 8-aligned, never straddles 128
                    const float* src = (k < 128)
                        ? ((const float*)A0v + (size_t)grow * 128 + k)
                        : (A1 + (size_t)grow * 128 + (k - 128));
                    float4 f0 = *(const float4*)src;
                    float4 f1 = *(const float4*)(src + 4);
                    pk.x = f2bf(f0.x) | (f2bf(f0.y) << 16);
                    pk.y = f2bf(f0.z) | (f2bf(f0.w) << 16);
                    pk.z = f2bf(f1.x) | (f2bf(f1.y) << 16);
                    pk.w = f2bf(f1.z) | (f2bf(f1.w) << 16);
                } else {
                    pk = *(const uint4*)((const u16*)A0v +
                                         (size_t)grow * 256 + k0 + kc);
                }
            }
            *(uint4*)&As[row][kc] = pk;
        }
#pragma unroll
        for (int i = 0; i < 4; ++i) {
            int idx = i * 256 + t;
            int n = idx >> 2, kc = (idx & 3) << 3;
            *(uint4*)&Bs[n][kc] = *(const uint4*)&WT[(size_t)n * 256 + k0 + kc];
        }
        __syncthreads();
        short8 af[4], bf[8];
#pragma unroll
        for (int mi = 0; mi < 4; ++mi)
            af[mi] = *(const short8*)&As[wm * 64 + mi * 16 + lr][kg * 8];
#pragma unroll
        for (int ni = 0; ni < 8; ++ni)
            bf[ni] = *(const short8*)&Bs[wn * 128 + ni * 16 + lr][kg * 8];
#pragma unroll
        for (int mi = 0; mi < 4; ++mi)
#pragma unroll
            for (int ni = 0; ni < 8; ++ni)
                acc[mi][ni] = __builtin_amdgcn_mfma_f32_16x16x32_bf16(
                    af[mi], bf[ni], acc[mi][ni], 0, 0, 0);
        __syncthreads();
    }

    const int orow = m0 + wm * 64;
    const int ocol = wn * 128;
#pragma unroll
    for (int mi = 0; mi < 4; ++mi) {
#pragma unroll
        for (int r = 0; r < 4; ++r) {
            int row = orow + mi * 16 + kg * 4 + r;
            if (row >= M) continue;
            float d = dis[row];
#pragma unroll
            for (int ni = 0; ni < 8; ++ni) {
                int col = ocol + ni * 16 + lr;
                float v = d * (acc[mi][ni][r] + bias[col]);
                if (W16) out16[(size_t)row * 256 + col] = (u16)f2bf(v);
                if (W8)  out8[(size_t)row * 256 + col] = f2fp8(v);
            }
        }
    }
}

// ----------------------------------------------------------- CSR aggregation
// fp8 rows (256B = 2 cache lines/edge). Wave per dst; half-wave covers the
// row with 8B/lane; 16 edges in flight per half-wave, branch-free via
// zero-row padding (index N_NODES).

static __device__ __forceinline__ void addf8(uint2 v, float* a) {
    auto f0 = __builtin_amdgcn_cvt_pk_f32_fp8((int)v.x, false);
    auto f1 = __builtin_amdgcn_cvt_pk_f32_fp8((int)v.x, true);
    auto f2 = __builtin_amdgcn_cvt_pk_f32_fp8((int)v.y, false);
    auto f3 = __builtin_amdgcn_cvt_pk_f32_fp8((int)v.y, true);
    a[0] += f0[0]; a[1] += f0[1]; a[2] += f1[0]; a[3] += f1[1];
    a[4] += f2[0]; a[5] += f2[1]; a[6] += f3[0]; a[7] += f3[1];
}

static __device__ __forceinline__ void gather_batch16_f8(
    const int* __restrict__ p, const u8* __restrict__ base, float* a) {
    int4 q0 = *(const int4*)p;              // ds_read_b128 broadcast
    int4 q1 = *(const int4*)(p + 4);
    int4 q2 = *(const int4*)(p + 8);
    int4 q3 = *(const int4*)(p + 12);
    uint2 v0  = *(const uint2*)(base + (size_t)q0.x * 256);
    uint2 v1  = *(const uint2*)(base + (size_t)q0.y * 256);
    uint2 v2  = *(const uint2*)(base + (size_t)q0.z * 256);
    uint2 v3  = *(const uint2*)(base + (size_t)q0.w * 256);
    uint2 v4  = *(const uint2*)(base + (size_t)q1.x * 256);
    uint2 v5  = *(const uint2*)(base + (size_t)q1.y * 256);
    uint2 v6  = *(const uint2*)(base + (size_t)q1.z * 256);
    uint2 v7  = *(const uint2*)(base + (size_t)q1.w * 256);
    uint2 v8  = *(const uint2*)(base + (size_t)q2.x * 256);
    uint2 v9  = *(const uint2*)(base + (size_t)q2.y * 256);
    uint2 v10 = *(const uint2*)(base + (size_t)q2.z * 256);
    uint2 v11 = *(const uint2*)(base + (size_t)q2.w * 256);
    uint2 v12 = *(const uint2*)(base + (size_t)q3.x * 256);
    uint2 v13 = *(const uint2*)(base + (size_t)q3.y * 256);
    uint2 v14 = *(const uint2*)(base + (size_t)q3.z * 256);
    uint2 v15 = *(const uint2*)(base + (size_t)q3.w * 256);
    addf8(v0, a);  addf8(v1, a);  addf8(v2, a);  addf8(v3, a);
    addf8(v4, a);  addf8(v5, a);  addf8(v6, a);  addf8(v7, a);
    addf8(v8, a);  addf8(v9, a);  addf8(v10, a); addf8(v11, a);
    addf8(v12, a); addf8(v13, a); addf8(v14, a); addf8(v15, a);
}

// agg1: h2(bf16) = relu(dis .* gather-sum(h1 fp8))
__global__ __launch_bounds__(256) void k_agg_f8(
    const int* __restrict__ rowptr, const int* __restrict__ rowend,
    const int* __restrict__ srcl, const u8* __restrict__ hs,
    const float* __restrict__ dis, u16* __restrict__ out) {
    __shared__ int idxb[4][64];
    int wave = threadIdx.x >> 6;
    int lane = threadIdx.x & 63;
    int half = lane >> 5;
    int c8 = lane & 31;                     // channel group (8 ch)
    int dst = blockIdx.x * 4 + wave;
    if (dst >= N_NODES) return;
    int s = rowptr[dst], e = rowend[dst];
    const u8* base = hs + c8 * 8;
    float a[8] = {0.f, 0.f, 0.f, 0.f, 0.f, 0.f, 0.f, 0.f};
    for (int k0 = s; k0 < e; k0 += 64) {
        int kk = k0 + lane;
        idxb[wave][lane] = (kk < e) ? __builtin_nontemporal_load(&srcl[kk])
                                    : N_NODES;           // zero row
        int nn = min(64, e - k0);
        for (int j = 0; j < nn; j += 32)
            gather_batch16_f8(&idxb[wave][j + half * 16], base, a);
    }
#pragma unroll
    for (int j = 0; j < 8; ++j) a[j] += __shfl_xor(a[j], 32, 64);
    if (half == 0) {
        float d = dis[dst];
        uint4 p;
        p.x = f2bf(fmaxf(a[0] * d, 0.f)) | (f2bf(fmaxf(a[1] * d, 0.f)) << 16);
        p.y = f2bf(fmaxf(a[2] * d, 0.f)) | (f2bf(fmaxf(a[3] * d, 0.f)) << 16);
        p.z = f2bf(fmaxf(a[4] * d, 0.f)) | (f2bf(fmaxf(a[5] * d, 0.f)) << 16);
        p.w = f2bf(fmaxf(a[6] * d, 0.f)) | (f2bf(fmaxf(a[7] * d, 0.f)) << 16);
        *(uint4*)&out[(size_t)dst * 256 + c8 * 8] = p;
    }
}

// agg2 + pool: fp8 gather, track per-channel packed (valbits,dst); exact
// value recovered by k_fix from bf16 h3. Values >= 0 so float-bit order ok.

static __device__ __forceinline__ ull packmd(float v, int dstid) {
    return ((ull)__float_as_uint(v) << 32) | (unsigned)dstid;
}

__global__ __launch_bounds__(256) void k_agg_pool_f8(
    const int* __restrict__ rowptr, const int* __restrict__ rowend,
    const int* __restrict__ srcl, const u8* __restrict__ hs,
    const float* __restrict__ dis, ull* __restrict__ gpool) {
    __shared__ int idxb[4][64];
    __shared__ ull lm[4][256];
    int wave = threadIdx.x >> 6;
    int lane = threadIdx.x & 63;
    int half = lane >> 5;
    int c8 = lane & 31;
    const u8* base = hs + c8 * 8;
    float m[8] = {0.f, 0.f, 0.f, 0.f, 0.f, 0.f, 0.f, 0.f};
    int   ad[8] = {0, 0, 0, 0, 0, 0, 0, 0};
    for (int dst = blockIdx.x * 4 + wave; dst < N_NODES;
         dst += POOL_BLOCKS * 4) {
        int s = rowptr[dst], e = rowend[dst];
        float a[8] = {0.f, 0.f, 0.f, 0.f, 0.f, 0.f, 0.f, 0.f};
        for (int k0 = s; k0 < e; k0 += 64) {
            int kk = k0 + lane;
            idxb[wave][lane] = (kk < e) ? __builtin_nontemporal_load(&srcl[kk])
                                        : N_NODES;       // zero row
            int nn = min(64, e - k0);
            for (int j = 0; j < nn; j += 32)
                gather_batch16_f8(&idxb[wave][j + half * 16], base, a);
        }
        float d = dis[dst];
#pragma unroll
        for (int j = 0; j < 8; ++j) {
            float v = (a[j] + __shfl_xor(a[j], 32, 64)) * d;
            if (v > m[j]) { m[j] = v; ad[j] = dst; }
        }
    }
    if (half == 0) {
#pragma unroll
        for (int j = 0; j < 8; ++j) lm[wave][c8 * 8 + j] = packmd(m[j], ad[j]);
    }
    __syncthreads();
    int t = threadIdx.x;
    ull v = lm[0][t];
    v = (lm[1][t] > v) ? lm[1][t] : v;
    v = (lm[2][t] > v) ? lm[2][t] : v;
    v = (lm[3][t] > v) ? lm[3][t] : v;
    atomicMax(&gpool[t], v);
}

// exact repair: re-aggregate each channel's winning dst from bf16 h3
__global__ __launch_bounds__(256) void k_fix(
    const ull* __restrict__ gpool, const int* __restrict__ rowptr,
    const int* __restrict__ rowend, const int* __restrict__ srcl,
    const u16* __restrict__ h3, const float* __restrict__ dis,
    float* __restrict__ g) {
    int t = threadIdx.x;                    // channel
    int dst = (int)(unsigned)(gpool[t] & 0xffffffffull);
    int s = rowptr[dst], e = rowend[dst];
    float sum = 0.f;
    for (int k = s; k < e; ++k) {
        int src = srcl[k];
        sum += bflo((unsigned)h3[(size_t)src * 256 + t]);
    }
    g[t] = fmaxf(dis[dst] * sum, 0.f);
}

// --------------------------------------------------------------------- head

__global__ __launch_bounds__(128) void k_head(
    const float* __restrict__ g, const float* __restrict__ Wp,
    const float* __restrict__ bp, const float* __restrict__ Wq,
    const float* __restrict__ bq, float* __restrict__ out) {
    __shared__ float sg[NHID];
    __shared__ float red[128];
    int t = threadIdx.x;
    sg[t] = g[t];
    sg[t + 128] = g[t + 128];
    __syncthreads();

    float v = 0.0f;
    if (t < NRES_P1) {
        float acc = bp[t];
        for (int k = 0; k < NHID; ++k) acc = fmaf(sg[k], Wp[k * NRES_P1 + t], acc);
        out[t] = acc;
        v = acc;
    }
    red[t] = (t < NRES_P1) ? v : -1e30f;
    __syncthreads();
#pragma unroll
    for (int off = 64; off > 0; off >>= 1) {
        if (t < off) red[t] = fmaxf(red[t], red[t + off]);
        __syncthreads();
    }
    float mx = red[0];
    __syncthreads();
    float ex = (t < NRES_P1) ? expf(v - mx) : 0.0f;
    red[t] = ex;
    __syncthreads();
#pragma unroll
    for (int off = 64; off > 0; off >>= 1) {
        if (t < off) red[t] += red[t + off];
        __syncthreads();
    }
    float sum = red[0];
    if (t < NRES_P1) out[NRES_P1 + t] = ex / sum;

    if (t < 64) {
        float a = fmaf(sg[t], Wq[t], 0.f);
        a = fmaf(sg[t + 64],  Wq[t + 64],  a);
        a = fmaf(sg[t + 128], Wq[t + 128], a);
        a = fmaf(sg[t + 192], Wq[t + 192], a);
#pragma unroll
        for (int off = 32; off > 0; off >>= 1) a += __shfl_down(a, off, 64);
        if (t == 0) out[2 * NRES_P1] = a + bq[0];
    }
}

// -------------------------------------------------------------------- launch

static inline size_t align256(size_t x) { return (x + 255) & ~size_t(255); }

extern "C" void kernel_launch(void* const* d_in, const int* in_sizes, int n_in,
                              void* d_out, int out_size, void* d_ws,
                              size_t ws_size, hipStream_t stream) {
    (void)in_sizes; (void)n_in; (void)out_size; (void)ws_size;
    const float* x    = (const float*)d_in[0];
    const float* feat = (const float*)d_in[1];
    const int*   ei   = (const int*)d_in[2];   // int32 (harness-converted)
    const float* W1   = (const float*)d_in[3];
    const float* b1   = (const float*)d_in[4];
    const float* W2   = (const float*)d_in[5];
    const float* b2   = (const float*)d_in[6];
    const float* Wp   = (const float*)d_in[7];
    const float* bp   = (const float*)d_in[8];
    const float* Wq   = (const float*)d_in[9];
    const float* bq   = (const float*)d_in[10];
    float* out = (float*)d_out;

    char* ws = (char*)d_ws;
    size_t off = 0;
    auto alloc = [&](size_t bytes) {
        void* p = ws + off;
        off = align256(off + bytes);
        return p;
    };
    int*   rowptr = (int*)alloc(4ull * N_NODES);
    int*   rowend = (int*)alloc(4ull * N_NODES);
    int*   srcl   = (int*)alloc(4ull * (N_EDGES + N_NODES));
    int*   estC   = (int*)alloc(4ull * (NBUCK + 1));
    int*   estR   = (int*)alloc(4ull * (NBUCK + 1));
    float* dis    = (float*)alloc(4ull * N_NODES);
    float* g      = (float*)alloc(4ull * NHID);
    ull*   gpool  = (ull*)alloc(8ull * NHID);
    u16*   W1T    = (u16*)alloc(2ull * 256 * 256);
    u16*   W2T    = (u16*)alloc(2ull * 256 * 256);
    u8*    buf1f8 = (u8*)alloc(1ull * (N_NODES + 1) * 256);  // h1 fp8 (+zero)
    u16*   buf2   = (u16*)alloc(2ull * N_NODES * 256);       // h2 bf16
    u16*   buf3   = (u16*)alloc(2ull * N_NODES * 256);       // h3 bf16 (exact)
    u8*    buf3f8 = (u8*)alloc(1ull * (N_NODES + 1) * 256);  // h3 fp8 (+zero)

    // transient prep buffers aliased into buf2/buf3 (dead before h2/h3 exist)
    int*      pC    = (int*)buf2;                            // 256*196 ints
    int*      pR    = pC  + 256 * NBUCK;
    int*      offC  = pR  + 256 * NBUCK;
    int*      offR  = offC + 256 * NBUCK;
    unsigned* sortC = (unsigned*)buf3;                       // 800k u32
    u16*      sortR = (u16*)((char*)buf3 + 4ull * N_EDGES);  // 800k u16

    hipMemsetAsync(gpool, 0, 8ull * NHID, stream);
    // zero rows (gather padding targets)
    hipMemsetAsync(buf1f8 + (size_t)N_NODES * 256, 0, 256, stream);
    hipMemsetAsync(buf3f8 + (size_t)N_NODES * 256, 0, 256, stream);

    k_prep_w2<<<64, 256, 0, stream>>>(W1, W2, W1T, W2T);
    k_bcount<<<256, 256, 0, stream>>>(ei, pC, pR);
    k_bscan<<<1, 256, 0, stream>>>(pC, pR, offC, offR, estC, estR);
    k_bscatter<<<256, 256, 0, stream>>>(ei, offC, offR, estC, estR,
                                        sortC, sortR);
    k_bcsr<<<NBUCK, 256, 0, stream>>>(sortC, estC, sortR, estR,
                                      rowptr, rowend, srcl, dis);

    const int gblocks = (N_NODES + 127) / 128;
    // conv1 linear -> h1 fp8
    k_gemm_mfma<true, false, true><<<gblocks, 256, 0, stream>>>(
        x, feat, W1T, b1, dis, nullptr, buf1f8, N_NODES);
    // agg1: h2 = bf16(relu(dis .* gather-sum(h1 fp8)))
    k_agg_f8<<<(N_NODES + 3) / 4, 256, 0, stream>>>(rowptr, rowend, srcl,
                                                    buf1f8, dis, buf2);
    // conv2 linear -> h3 bf16 (exact) + fp8 (gather)
    k_gemm_mfma<false, true, true><<<gblocks, 256, 0, stream>>>(
        buf2, nullptr, W2T, b2, dis, buf3, buf3f8, N_NODES);
    // agg2 + pool: approx max + argmax via fp8
    k_agg_pool_f8<<<POOL_BLOCKS, 256, 0, stream>>>(rowptr, rowend, srcl,
                                                   buf3f8, dis, gpool);
    // exact repair of the winning dst per channel
    k_fix<<<1, 256, 0, stream>>>(gpool, rowptr, rowend, srcl, buf3, dis, g);

    k_head<<<1, 128, 0, stream>>>(g, Wp, bp, Wq, bq, out);
}

// Round 12
// 227.978 us; speedup vs baseline: 1.4773x; 1.1435x over previous
//
#include <hip/hip_runtime.h>

#define N_NODES 50000
#define N_EDGES 800000
#define NHID    256
#define NRES_P1 101

#define NBUCK   196            // node buckets (node >> 8), 50000/256 -> 196
#define EPB     3125           // edges per scatter block (256 blocks exactly)
#define BCAP    6144           // per-bucket staging cap
#define POOL_BLOCKS 2048       // fused agg2+pool grid

typedef unsigned short u16;
typedef unsigned char  u8;
typedef unsigned long long ull;
typedef __attribute__((ext_vector_type(8))) short short8;   // 8 bf16
typedef __attribute__((ext_vector_type(4))) float f32x4;

static __device__ __forceinline__ unsigned f2bf(float f) {  // RNE -> low 16
    unsigned u = __float_as_uint(f);
    return (u + 0x7FFF + ((u >> 16) & 1)) >> 16;
}
static __device__ __forceinline__ float bflo(unsigned p) {
    return __uint_as_float(p << 16);
}
static __device__ __forceinline__ u8 f2fp8(float f) {       // HW e4m3 (OCP)
    return (u8)(__builtin_amdgcn_cvt_pk_fp8_f32(f, f, 0, false) & 0xff);
}

// --------------------------------------------- graph prep: bucket sort

__global__ __launch_bounds__(256) void k_bcount(
    const int* __restrict__ ei, int* __restrict__ pC, int* __restrict__ pR) {
    __shared__ int cC[NBUCK], cR[NBUCK];
    int b = blockIdx.x, t = threadIdx.x;
    if (t < NBUCK) { cC[t] = 0; cR[t] = 0; }
    __syncthreads();
    int base = b * EPB;
    for (int i = t; i < EPB; i += 256) {
        int r = ei[base + i];
        int c = ei[N_EDGES + base + i];
        atomicAdd(&cR[r >> 8], 1);
        atomicAdd(&cC[c >> 8], 1);
    }
    __syncthreads();
    if (t < NBUCK) { pC[b * NBUCK + t] = cC[t]; pR[b * NBUCK + t] = cR[t]; }
}

__global__ __launch_bounds__(256) void k_bscan(
    const int* __restrict__ pC, const int* __restrict__ pR,
    int* __restrict__ offC, int* __restrict__ offR,
    int* __restrict__ estC, int* __restrict__ estR) {
    __shared__ int totC[NBUCK], totR[NBUCK];
    int t = threadIdx.x;
    if (t < NBUCK) {
        int runC = 0, runR = 0;
        for (int b = 0; b < 256; b += 8) {
            int vc[8], vr[8];
#pragma unroll
            for (int j = 0; j < 8; ++j) {
                vc[j] = pC[(b + j) * NBUCK + t];
                vr[j] = pR[(b + j) * NBUCK + t];
            }
#pragma unroll
            for (int j = 0; j < 8; ++j) {
                offC[t * 256 + b + j] = runC; runC += vc[j];
                offR[t * 256 + b + j] = runR; runR += vr[j];
            }
        }
        totC[t] = runC; totR[t] = runR;
    }
    __syncthreads();
    if (t == 0) {
        int rc = 0, rr = 0;
        for (int k = 0; k < NBUCK; ++k) {
            estC[k] = rc; rc += totC[k];
            estR[k] = rr; rr += totR[k];
        }
        estC[NBUCK] = rc; estR[NBUCK] = rr;
    }
}

__global__ __launch_bounds__(256) void k_bscatter(
    const int* __restrict__ ei, const int* __restrict__ offC,
    const int* __restrict__ offR, const int* __restrict__ estC,
    const int* __restrict__ estR, unsigned* __restrict__ sortC,
    u16* __restrict__ sortR) {
    __shared__ int curC[NBUCK], curR[NBUCK];
    int b = blockIdx.x, t = threadIdx.x;
    if (t < NBUCK) {
        curC[t] = estC[t] + offC[t * 256 + b];
        curR[t] = estR[t] + offR[t * 256 + b];
    }
    __syncthreads();
    int base = b * EPB;
    for (int i = t; i < EPB; i += 256) {
        int r = ei[base + i];
        int c = ei[N_EDGES + base + i];
        int pc = atomicAdd(&curC[c >> 8], 1);
        sortC[pc] = ((unsigned)(c & 255) << 16) | (unsigned)r;  // r < 65536
        int pr = atomicAdd(&curR[r >> 8], 1);
        sortR[pr] = (u16)(r & 255);
    }
}

// per-bucket exact CSR + out-degree -> dis
__global__ __launch_bounds__(256) void k_bcsr(
    const unsigned* __restrict__ sortC, const int* __restrict__ estC,
    const u16* __restrict__ sortR, const int* __restrict__ estR,
    int* __restrict__ rowptr, int* __restrict__ rowend,
    int* __restrict__ srcl, float* __restrict__ dis) {
    __shared__ int hist[256], cur[256], excl[256], hist2[256];
    __shared__ int wsum[4], woff[4];
    __shared__ unsigned stg[BCAP];
    int k = blockIdx.x, t = threadIdx.x;
    int lane = t & 63, wid = t >> 6;
    int nloc = min(256, N_NODES - k * 256);
    int es = estC[k], ee = estC[k + 1];
    int ecnt = ee - es;
    int fs = es + k * 256;
    hist[t] = 0; cur[t] = 0; hist2[t] = 0;
    __syncthreads();
    for (int i = t; i < ecnt; i += 256)
        atomicAdd(&hist[sortC[es + i] >> 16], 1);
    {
        int rs = estR[k], rcnt = estR[k + 1] - rs;
        for (int i = t; i < rcnt; i += 256)
            atomicAdd(&hist2[(int)sortR[rs + i]], 1);
    }
    __syncthreads();
    if (t < nloc) dis[k * 256 + t] = rsqrtf((float)(hist2[t] + 1));
    int sv = hist[t] + (t < nloc ? 1 : 0);
    int sc = sv;
#pragma unroll
    for (int off = 1; off < 64; off <<= 1) {
        int y = __shfl_up(sc, off, 64);
        if (lane >= off) sc += y;
    }
    if (lane == 63) wsum[wid] = sc;
    __syncthreads();
    if (t == 0) {
        int r = 0;
#pragma unroll
        for (int w = 0; w < 4; ++w) { woff[w] = r; r += wsum[w]; }
    }
    __syncthreads();
    int ex = woff[wid] + sc - sv;
    excl[t] = ex;
    if (t < nloc) {
        rowptr[k * 256 + t] = fs + ex;
        rowend[k * 256 + t] = fs + ex + hist[t] + 1;
    }
    __syncthreads();
    int tot = ecnt + nloc;
    if (tot <= BCAP) {
        for (int i = t; i < ecnt; i += 256) {
            unsigned v = sortC[es + i];
            int j = v >> 16;
            int p = excl[j] + atomicAdd(&cur[j], 1);
            stg[p] = v & 0xffffu;
        }
        if (t < nloc) stg[excl[t] + hist[t]] = (unsigned)(k * 256 + t);
        __syncthreads();
        for (int i = t; i < tot; i += 256) srcl[fs + i] = (int)stg[i];
    } else {
        for (int i = t; i < ecnt; i += 256) {
            unsigned v = sortC[es + i];
            int j = v >> 16;
            int p = excl[j] + atomicAdd(&cur[j], 1);
            srcl[fs + p] = (int)(v & 0xffffu);
        }
        if (t < nloc) srcl[fs + excl[t] + hist[t]] = k * 256 + t;
    }
}

// weight transposes + zero-fills (fused memsets): WT[n][k] = bf16(W[k][n])
__global__ void k_prep_w2(const float* __restrict__ W1, const float* __restrict__ W2,
                          u16* __restrict__ W1T, u16* __restrict__ W2T,
                          ull* __restrict__ gpool, u8* __restrict__ z1,
                          u8* __restrict__ z2) {
    int tid = blockIdx.x * 256 + threadIdx.x;    // 16384
    if (blockIdx.x == 0) {
        int t = threadIdx.x;
        gpool[t] = 0ull;
        if (t < 64) {                             // 256B zero rows
            ((unsigned*)z1)[t] = 0u;
            ((unsigned*)z2)[t] = 0u;
        }
    }
    const float* W = (tid < 8192) ? W1 : W2;
    u16* WT = (tid < 8192) ? W1T : W2T;
    int id = tid & 8191;
    int n = id >> 5, k8 = (id & 31) << 3;
    u16 tmp[8];
#pragma unroll
    for (int i = 0; i < 8; ++i) tmp[i] = (u16)f2bf(W[(size_t)(k8 + i) * 256 + n]);
    *(uint4*)&WT[(size_t)n * 256 + k8] = *(uint4*)tmp;
}

// ------------------------------------------------------------- MFMA GEMM
// out8 = fp8( dis[m] * ( A @ W + bias ) ).  BM=128, BN=256, BK=32.
// LDS rows 64B (linear, no pad); bank spread via XOR chunk swizzle
// c' = c ^ ((row>>1)&3), applied on the per-lane GLOBAL source address
// (LDS dest stays linear for global_load_lds) and on fragment ds_reads.
// SPLIT: A = concat(x,feat) f32 -> bf16 in VGPR staging (swizzled ds_write);
// else A staged via global_load_lds width=16 (tail rows read adjacent ws
// scratch — harmless, results discarded by the row<M epilogue guard).

template <bool SPLIT>
__global__ __launch_bounds__(256, 2) void k_gemm_mfma(
    const void* __restrict__ A0v, const float* __restrict__ A1,
    const u16* __restrict__ WT, const float* __restrict__ bias,
    const float* __restrict__ dis, u8* __restrict__ out8, int M) {
    __shared__ u16 As[128][32];
    __shared__ u16 Bs[256][32];
    const int t = threadIdx.x;
    const int m0 = blockIdx.x * 128;
    const int lane = t & 63, wave = t >> 6;
    const int wm = wave & 1, wn = wave >> 1;
    const int lr = lane & 15, kg = lane >> 4;

    f32x4 acc[4][8] = {};

    for (int k0 = 0; k0 < 256; k0 += 32) {
        // ---- A tile: 128 rows x 64B
        if (SPLIT) {
#pragma unroll
            for (int i = 0; i < 2; ++i) {
                int idx = i * 256 + t;
                int row = idx >> 2, c = idx & 3;
                int cl = c ^ ((row >> 1) & 3);       // logical chunk at this slot
                int grow = m0 + row;
                uint4 pk = {0u, 0u, 0u, 0u};
                if (grow < M) {
                    int k = k0 + cl * 8;             // 8-aligned
                    const float* src = (k < 128)
                        ? ((const float*)A0v + (size_t)grow * 128 + k)
                        : (A1 + (size_t)grow * 128 + (k - 128));
                    float4 f0 = *(const float4*)src;
                    float4 f1 = *(const float4*)(src + 4);
                    pk.x = f2bf(f0.x) | (f2bf(f0.y) << 16);
                    pk.y = f2bf(f0.z) | (f2bf(f0.w) << 16);
                    pk.z = f2bf(f1.x) | (f2bf(f1.y) << 16);
                    pk.w = f2bf(f1.z) | (f2bf(f1.w) << 16);
                }
                *(uint4*)&As[row][c * 8] = pk;
            }
        } else {
#pragma unroll
            for (int i = 0; i < 2; ++i) {
                int idx = i * 256 + t;
                int row = idx >> 2, c = idx & 3;
                int cl = c ^ ((row >> 1) & 3);
                const u16* src = (const u16*)A0v + (size_t)(m0 + row) * 256
                                 + k0 + cl * 8;
                __builtin_amdgcn_global_load_lds(
                    (const __attribute__((address_space(1))) void*)src,
                    (__attribute__((address_space(3))) void*)
                        ((char*)&As[0][0] + ((i * 256 + wave * 64) << 4)),
                    16, 0, 0);
            }
        }
        // ---- B tile: 256 rows x 64B via global_load_lds
#pragma unroll
        for (int i = 0; i < 4; ++i) {
            int idx = i * 256 + t;
            int row = idx >> 2, c = idx & 3;
            int cl = c ^ ((row >> 1) & 3);
            const u16* src = WT + (size_t)row * 256 + k0 + cl * 8;
            __builtin_amdgcn_global_load_lds(
                (const __attribute__((address_space(1))) void*)src,
                (__attribute__((address_space(3))) void*)
                    ((char*)&Bs[0][0] + ((i * 256 + wave * 64) << 4)),
                16, 0, 0);
        }
        __syncthreads();
        short8 af[4], bfr[8];
#pragma unroll
        for (int mi = 0; mi < 4; ++mi) {
            int row = wm * 64 + mi * 16 + lr;
            af[mi] = *(const short8*)&As[row][(kg ^ ((row >> 1) & 3)) * 8];
        }
#pragma unroll
        for (int ni = 0; ni < 8; ++ni) {
            int row = wn * 128 + ni * 16 + lr;
            bfr[ni] = *(const short8*)&Bs[row][(kg ^ ((row >> 1) & 3)) * 8];
        }
#pragma unroll
        for (int mi = 0; mi < 4; ++mi)
#pragma unroll
            for (int ni = 0; ni < 8; ++ni)
                acc[mi][ni] = __builtin_amdgcn_mfma_f32_16x16x32_bf16(
                    af[mi], bfr[ni], acc[mi][ni], 0, 0, 0);
        __syncthreads();
    }

    const int orow = m0 + wm * 64;
    const int ocol = wn * 128;
#pragma unroll
    for (int mi = 0; mi < 4; ++mi) {
#pragma unroll
        for (int r = 0; r < 4; ++r) {
            int row = orow + mi * 16 + kg * 4 + r;
            if (row >= M) continue;
            float d = dis[row];
#pragma unroll
            for (int ni = 0; ni < 8; ++ni) {
                int col = ocol + ni * 16 + lr;
                out8[(size_t)row * 256 + col] =
                    f2fp8(d * (acc[mi][ni][r] + bias[col]));
            }
        }
    }
}

// ----------------------------------------------------------- CSR aggregation
// fp8 rows (256B = 2 cache lines/edge). Wave per dst; half-wave covers the
// row with 8B/lane; 16 edges in flight per half-wave, branch-free via
// zero-row padding (index N_NODES).

static __device__ __forceinline__ void addf8(uint2 v, float* a) {
    auto f0 = __builtin_amdgcn_cvt_pk_f32_fp8((int)v.x, false);
    auto f1 = __builtin_amdgcn_cvt_pk_f32_fp8((int)v.x, true);
    auto f2 = __builtin_amdgcn_cvt_pk_f32_fp8((int)v.y, false);
    auto f3 = __builtin_amdgcn_cvt_pk_f32_fp8((int)v.y, true);
    a[0] += f0[0]; a[1] += f0[1]; a[2] += f1[0]; a[3] += f1[1];
    a[4] += f2[0]; a[5] += f2[1]; a[6] += f3[0]; a[7] += f3[1];
}

static __device__ __forceinline__ void gather_batch16_f8(
    const int* __restrict__ p, const u8* __restrict__ base, float* a) {
    int4 q0 = *(const int4*)p;
    int4 q1 = *(const int4*)(p + 4);
    int4 q2 = *(const int4*)(p + 8);
    int4 q3 = *(const int4*)(p + 12);
    uint2 v0  = *(const uint2*)(base + (size_t)q0.x * 256);
    uint2 v1  = *(const uint2*)(base + (size_t)q0.y * 256);
    uint2 v2  = *(const uint2*)(base + (size_t)q0.z * 256);
    uint2 v3  = *(const uint2*)(base + (size_t)q0.w * 256);
    uint2 v4  = *(const uint2*)(base + (size_t)q1.x * 256);
    uint2 v5  = *(const uint2*)(base + (size_t)q1.y * 256);
    uint2 v6  = *(const uint2*)(base + (size_t)q1.z * 256);
    uint2 v7  = *(const uint2*)(base + (size_t)q1.w * 256);
    uint2 v8  = *(const uint2*)(base + (size_t)q2.x * 256);
    uint2 v9  = *(const uint2*)(base + (size_t)q2.y * 256);
    uint2 v10 = *(const uint2*)(base + (size_t)q2.z * 256);
    uint2 v11 = *(const uint2*)(base + (size_t)q2.w * 256);
    uint2 v12 = *(const uint2*)(base + (size_t)q3.x * 256);
    uint2 v13 = *(const uint2*)(base + (size_t)q3.y * 256);
    uint2 v14 = *(const uint2*)(base + (size_t)q3.z * 256);
    uint2 v15 = *(const uint2*)(base + (size_t)q3.w * 256);
    addf8(v0, a);  addf8(v1, a);  addf8(v2, a);  addf8(v3, a);
    addf8(v4, a);  addf8(v5, a);  addf8(v6, a);  addf8(v7, a);
    addf8(v8, a);  addf8(v9, a);  addf8(v10, a); addf8(v11, a);
    addf8(v12, a); addf8(v13, a); addf8(v14, a); addf8(v15, a);
}

__global__ __launch_bounds__(256) void k_agg_f8(
    const int* __restrict__ rowptr, const int* __restrict__ rowend,
    const int* __restrict__ srcl, const u8* __restrict__ hs,
    const float* __restrict__ dis, u16* __restrict__ out) {
    __shared__ int idxb[4][64];
    int wave = threadIdx.x >> 6;
    int lane = threadIdx.x & 63;
    int half = lane >> 5;
    int c8 = lane & 31;
    int dst = blockIdx.x * 4 + wave;
    if (dst >= N_NODES) return;
    int s = rowptr[dst], e = rowend[dst];
    const u8* base = hs + c8 * 8;
    float a[8] = {0.f, 0.f, 0.f, 0.f, 0.f, 0.f, 0.f, 0.f};
    for (int k0 = s; k0 < e; k0 += 64) {
        int kk = k0 + lane;
        idxb[wave][lane] = (kk < e) ? __builtin_nontemporal_load(&srcl[kk])
                                    : N_NODES;
        int nn = min(64, e - k0);
        for (int j = 0; j < nn; j += 32)
            gather_batch16_f8(&idxb[wave][j + half * 16], base, a);
    }
#pragma unroll
    for (int j = 0; j < 8; ++j) a[j] += __shfl_xor(a[j], 32, 64);
    if (half == 0) {
        float d = dis[dst];
        uint4 p;
        p.x = f2bf(fmaxf(a[0] * d, 0.f)) | (f2bf(fmaxf(a[1] * d, 0.f)) << 16);
        p.y = f2bf(fmaxf(a[2] * d, 0.f)) | (f2bf(fmaxf(a[3] * d, 0.f)) << 16);
        p.z = f2bf(fmaxf(a[4] * d, 0.f)) | (f2bf(fmaxf(a[5] * d, 0.f)) << 16);
        p.w = f2bf(fmaxf(a[6] * d, 0.f)) | (f2bf(fmaxf(a[7] * d, 0.f)) << 16);
        *(uint4*)&out[(size_t)dst * 256 + c8 * 8] = p;
    }
}

static __device__ __forceinline__ ull packmd(float v, int dstid) {
    return ((ull)__float_as_uint(v) << 32) | (unsigned)dstid;
}

__global__ __launch_bounds__(256) void k_agg_pool_f8(
    const int* __restrict__ rowptr, const int* __restrict__ rowend,
    const int* __restrict__ srcl, const u8* __restrict__ hs,
    const float* __restrict__ dis, ull* __restrict__ gpool) {
    __shared__ int idxb[4][64];
    __shared__ ull lm[4][256];
    int wave = threadIdx.x >> 6;
    int lane = threadIdx.x & 63;
    int half = lane >> 5;
    int c8 = lane & 31;
    const u8* base = hs + c8 * 8;
    float m[8] = {0.f, 0.f, 0.f, 0.f, 0.f, 0.f, 0.f, 0.f};
    int   ad[8] = {0, 0, 0, 0, 0, 0, 0, 0};
    for (int dst = blockIdx.x * 4 + wave; dst < N_NODES;
         dst += POOL_BLOCKS * 4) {
        int s = rowptr[dst], e = rowend[dst];
        float a[8] = {0.f, 0.f, 0.f, 0.f, 0.f, 0.f, 0.f, 0.f};
        for (int k0 = s; k0 < e; k0 += 64) {
            int kk = k0 + lane;
            idxb[wave][lane] = (kk < e) ? __builtin_nontemporal_load(&srcl[kk])
                                        : N_NODES;
            int nn = min(64, e - k0);
            for (int j = 0; j < nn; j += 32)
                gather_batch16_f8(&idxb[wave][j + half * 16], base, a);
        }
        float d = dis[dst];
#pragma unroll
        for (int j = 0; j < 8; ++j) {
            float v = (a[j] + __shfl_xor(a[j], 32, 64)) * d;
            if (v > m[j]) { m[j] = v; ad[j] = dst; }
        }
    }
    if (half == 0) {
#pragma unroll
        for (int j = 0; j < 8; ++j) lm[wave][c8 * 8 + j] = packmd(m[j], ad[j]);
    }
    __syncthreads();
    int t = threadIdx.x;
    ull v = lm[0][t];
    v = (lm[1][t] > v) ? lm[1][t] : v;
    v = (lm[2][t] > v) ? lm[2][t] : v;
    v = (lm[3][t] > v) ? lm[3][t] : v;
    atomicMax(&gpool[t], v);
}

// exact repair from h2 + W2:  sum_src h3[src] = (sum_src dis[src]*h2[src])@W2
//                                              + b2 * sum_src dis[src]
__global__ __launch_bounds__(256) void k_fix(
    const ull* __restrict__ gpool, const int* __restrict__ rowptr,
    const int* __restrict__ rowend, const int* __restrict__ srcl,
    const u16* __restrict__ h2, const u16* __restrict__ W2T,
    const float* __restrict__ b2, const float* __restrict__ dis,
    float* __restrict__ g) {
    __shared__ float red[256];
    __shared__ int   sidx[128];
    __shared__ float sdis[128];
    __shared__ float Dsh;
    int b = blockIdx.x;                     // channel
    int t = threadIdx.x;                    // k index
    int dst = (int)(unsigned)(gpool[b] & 0xffffffffull);
    int s = rowptr[dst], e = rowend[dst];
    int n = e - s;
    float uk = 0.f;
    if (t == 0) Dsh = 0.f;
    for (int c0 = 0; c0 < n; c0 += 128) {
        int nn = min(128, n - c0);
        __syncthreads();
        for (int i = t; i < nn; i += 256) {
            int sr = srcl[s + c0 + i];
            sidx[i] = sr; sdis[i] = dis[sr];
        }
        __syncthreads();
        int i = 0;
        for (; i + 4 <= nn; i += 4) {       // 4 loads in flight
            float v0 = bflo((unsigned)h2[(size_t)sidx[i]     * 256 + t]);
            float v1 = bflo((unsigned)h2[(size_t)sidx[i + 1] * 256 + t]);
            float v2 = bflo((unsigned)h2[(size_t)sidx[i + 2] * 256 + t]);
            float v3 = bflo((unsigned)h2[(size_t)sidx[i + 3] * 256 + t]);
            uk += sdis[i] * v0 + sdis[i + 1] * v1
                + sdis[i + 2] * v2 + sdis[i + 3] * v3;
        }
        for (; i < nn; ++i)
            uk += sdis[i] * bflo((unsigned)h2[(size_t)sidx[i] * 256 + t]);
        if (t == 0) {
            float dl = 0.f;
            for (int q = 0; q < nn; ++q) dl += sdis[q];
            Dsh += dl;
        }
    }
    float w = bflo((unsigned)W2T[(size_t)b * 256 + t]);
    red[t] = uk * w;
    __syncthreads();
#pragma unroll
    for (int off = 128; off > 0; off >>= 1) {
        if (t < off) red[t] += red[t + off];
        __syncthreads();
    }
    if (t == 0) {
        float val = red[0] + b2[b] * Dsh;
        g[b] = fmaxf(dis[dst] * val, 0.f);
    }
}

// --------------------------------------------------------------------- head

__global__ __launch_bounds__(128) void k_head(
    const float* __restrict__ g, const float* __restrict__ Wp,
    const float* __restrict__ bp, const float* __restrict__ Wq,
    const float* __restrict__ bq, float* __restrict__ out) {
    __shared__ float sg[NHID];
    __shared__ float red[128];
    int t = threadIdx.x;
    sg[t] = g[t];
    sg[t + 128] = g[t + 128];
    __syncthreads();

    float v = 0.0f;
    if (t < NRES_P1) {
        float acc = bp[t];
        for (int k = 0; k < NHID; ++k) acc = fmaf(sg[k], Wp[k * NRES_P1 + t], acc);
        out[t] = acc;
        v = acc;
    }
    red[t] = (t < NRES_P1) ? v : -1e30f;
    __syncthreads();
#pragma unroll
    for (int off = 64; off > 0; off >>= 1) {
        if (t < off) red[t] = fmaxf(red[t], red[t + off]);
        __syncthreads();
    }
    float mx = red[0];
    __syncthreads();
    float ex = (t < NRES_P1) ? expf(v - mx) : 0.0f;
    red[t] = ex;
    __syncthreads();
#pragma unroll
    for (int off = 64; off > 0; off >>= 1) {
        if (t < off) red[t] += red[t + off];
        __syncthreads();
    }
    float sum = red[0];
    if (t < NRES_P1) out[NRES_P1 + t] = ex / sum;

    if (t < 64) {
        float a = fmaf(sg[t], Wq[t], 0.f);
        a = fmaf(sg[t + 64],  Wq[t + 64],  a);
        a = fmaf(sg[t + 128], Wq[t + 128], a);
        a = fmaf(sg[t + 192], Wq[t + 192], a);
#pragma unroll
        for (int off = 32; off > 0; off >>= 1) a += __shfl_down(a, off, 64);
        if (t == 0) out[2 * NRES_P1] = a + bq[0];
    }
}

// -------------------------------------------------------------------- launch

static inline size_t align256(size_t x) { return (x + 255) & ~size_t(255); }

extern "C" void kernel_launch(void* const* d_in, const int* in_sizes, int n_in,
                              void* d_out, int out_size, void* d_ws,
                              size_t ws_size, hipStream_t stream) {
    (void)in_sizes; (void)n_in; (void)out_size; (void)ws_size;
    const float* x    = (const float*)d_in[0];
    const float* feat = (const float*)d_in[1];
    const int*   ei   = (const int*)d_in[2];   // int32 (harness-converted)
    const float* W1   = (const float*)d_in[3];
    const float* b1   = (const float*)d_in[4];
    const float* W2   = (const float*)d_in[5];
    const float* b2   = (const float*)d_in[6];
    const float* Wp   = (const float*)d_in[7];
    const float* bp   = (const float*)d_in[8];
    const float* Wq   = (const float*)d_in[9];
    const float* bq   = (const float*)d_in[10];
    float* out = (float*)d_out;

    char* ws = (char*)d_ws;
    size_t off = 0;
    auto alloc = [&](size_t bytes) {
        void* p = ws + off;
        off = align256(off + bytes);
        return p;
    };
    int*   rowptr = (int*)alloc(4ull * N_NODES);
    int*   rowend = (int*)alloc(4ull * N_NODES);
    int*   srcl   = (int*)alloc(4ull * (N_EDGES + N_NODES));
    int*   estC   = (int*)alloc(4ull * (NBUCK + 1));
    int*   estR   = (int*)alloc(4ull * (NBUCK + 1));
    float* dis    = (float*)alloc(4ull * N_NODES);
    float* g      = (float*)alloc(4ull * NHID);
    ull*   gpool  = (ull*)alloc(8ull * NHID);
    u16*   W1T    = (u16*)alloc(2ull * 256 * 256);
    u16*   W2T    = (u16*)alloc(2ull * 256 * 256);
    u8*    buf1f8 = (u8*)alloc(1ull * (N_NODES + 1) * 256);  // h1 fp8 (+zero)
    u16*   buf2   = (u16*)alloc(2ull * N_NODES * 256);       // h2 bf16
    u8*    buf3f8 = (u8*)alloc(1ull * (N_NODES + 1) * 256);  // h3 fp8 (+zero)
    alloc(64 * 1024);   // tail guard: gemm2 A-tile OOB global_load_lds reads

    // transient sort buffers aliased into buf2 (dead before h2 is written)
    int*      pC    = (int*)buf2;                            // 256*196 ints
    int*      pR    = pC  + 256 * NBUCK;
    int*      offC  = pR  + 256 * NBUCK;
    int*      offR  = offC + 256 * NBUCK;
    unsigned* sortC = (unsigned*)(offR + 256 * NBUCK);       // 800k u32
    u16*      sortR = (u16*)(sortC + N_EDGES);               // 800k u16

    k_prep_w2<<<64, 256, 0, stream>>>(W1, W2, W1T, W2T, gpool,
                                      buf1f8 + (size_t)N_NODES * 256,
                                      buf3f8 + (size_t)N_NODES * 256);
    k_bcount<<<256, 256, 0, stream>>>(ei, pC, pR);
    k_bscan<<<1, 256, 0, stream>>>(pC, pR, offC, offR, estC, estR);
    k_bscatter<<<256, 256, 0, stream>>>(ei, offC, offR, estC, estR,
                                        sortC, sortR);
    k_bcsr<<<NBUCK, 256, 0, stream>>>(sortC, estC, sortR, estR,
                                      rowptr, rowend, srcl, dis);

    const int gblocks = (N_NODES + 127) / 128;
    // conv1 linear -> h1 fp8
    k_gemm_mfma<true><<<gblocks, 256, 0, stream>>>(
        x, feat, W1T, b1, dis, buf1f8, N_NODES);
    // agg1: h2 = bf16(relu(dis .* gather-sum(h1 fp8)))
    k_agg_f8<<<(N_NODES + 3) / 4, 256, 0, stream>>>(rowptr, rowend, srcl,
                                                    buf1f8, dis, buf2);
    // conv2 linear -> h3 fp8 only
    k_gemm_mfma<false><<<gblocks, 256, 0, stream>>>(
        buf2, nullptr, W2T, b2, dis, buf3f8, N_NODES);
    // agg2 + pool: approx max + argmax via fp8
    k_agg_pool_f8<<<POOL_BLOCKS, 256, 0, stream>>>(rowptr, rowend, srcl,
                                                   buf3f8, dis, gpool);
    // exact repair of the winning dst per channel (from h2 + W2)
    k_fix<<<NHID, 256, 0, stream>>>(gpool, rowptr, rowend, srcl,
                                    buf2, W2T, b2, dis, g);

    k_head<<<1, 128, 0, stream>>>(g, Wp, bp, Wq, bq, out);
}

// Round 13
// 219.675 us; speedup vs baseline: 1.5331x; 1.0378x over previous
//
#include <hip/hip_runtime.h>

#define N_NODES 50000
#define N_EDGES 800000
#define NHID    256
#define NRES_P1 101

#define NBUCK   196            // node buckets (node >> 8), 50000/256 -> 196
#define EPB     3125           // edges per scatter block (256 blocks exactly)
#define BCAP    6144           // per-bucket staging cap
#define POOL_BLOCKS 2048       // fused agg2+pool grid

typedef unsigned short u16;
typedef unsigned char  u8;
typedef unsigned long long ull;
typedef __attribute__((ext_vector_type(8))) short short8;   // 8 bf16
typedef __attribute__((ext_vector_type(4))) float f32x4;
typedef __attribute__((ext_vector_type(2))) float f32x2;

static __device__ __forceinline__ unsigned f2bf(float f) {  // RNE -> low 16
    unsigned u = __float_as_uint(f);
    return (u + 0x7FFF + ((u >> 16) & 1)) >> 16;
}
static __device__ __forceinline__ float bflo(unsigned p) {
    return __uint_as_float(p << 16);
}
static __device__ __forceinline__ u8 f2fp8(float f) {       // HW e4m3 (OCP)
    return (u8)(__builtin_amdgcn_cvt_pk_fp8_f32(f, f, 0, false) & 0xff);
}

// ------------------------------------------ prep: bucket count + weight prep
// blocks 0..255: per-block bucket histograms of c>>8 and r>>8
// blocks 256..319: WT[n][k] = bf16(W[k][n]); block 256 also zero-fills

__global__ __launch_bounds__(256) void k_prep(
    const int* __restrict__ ei, int* __restrict__ pC, int* __restrict__ pR,
    const float* __restrict__ W1, const float* __restrict__ W2,
    u16* __restrict__ W1T, u16* __restrict__ W2T,
    ull* __restrict__ gpool, u8* __restrict__ z1, u8* __restrict__ z2) {
    __shared__ int cC[NBUCK], cR[NBUCK];
    int b = blockIdx.x, t = threadIdx.x;
    if (b < 256) {
        if (t < NBUCK) { cC[t] = 0; cR[t] = 0; }
        __syncthreads();
        int base = b * EPB;
        for (int i = t; i < EPB; i += 256) {
            int r = ei[base + i];
            int c = ei[N_EDGES + base + i];
            atomicAdd(&cR[r >> 8], 1);
            atomicAdd(&cC[c >> 8], 1);
        }
        __syncthreads();
        if (t < NBUCK) { pC[b * NBUCK + t] = cC[t]; pR[b * NBUCK + t] = cR[t]; }
    } else {
        if (b == 256) {
            gpool[t] = 0ull;
            if (t < 64) {                         // 256B zero rows
                ((unsigned*)z1)[t] = 0u;
                ((unsigned*)z2)[t] = 0u;
            }
        }
        int tid = (b - 256) * 256 + t;            // 0..16383
        const float* W = (tid < 8192) ? W1 : W2;
        u16* WT = (tid < 8192) ? W1T : W2T;
        int id = tid & 8191;
        int n = id >> 5, k8 = (id & 31) << 3;
        u16 tmp[8];
#pragma unroll
        for (int i = 0; i < 8; ++i)
            tmp[i] = (u16)f2bf(W[(size_t)(k8 + i) * 256 + n]);
        *(uint4*)&WT[(size_t)n * 256 + k8] = *(uint4*)tmp;
    }
}

__global__ __launch_bounds__(256) void k_bscan(
    const int* __restrict__ pC, const int* __restrict__ pR,
    int* __restrict__ offC, int* __restrict__ offR,
    int* __restrict__ estC, int* __restrict__ estR) {
    __shared__ int totC[NBUCK], totR[NBUCK];
    int t = threadIdx.x;
    if (t < NBUCK) {
        int runC = 0, runR = 0;
        for (int b = 0; b < 256; b += 8) {
            int vc[8], vr[8];
#pragma unroll
            for (int j = 0; j < 8; ++j) {
                vc[j] = pC[(b + j) * NBUCK + t];
                vr[j] = pR[(b + j) * NBUCK + t];
            }
#pragma unroll
            for (int j = 0; j < 8; ++j) {
                offC[t * 256 + b + j] = runC; runC += vc[j];
                offR[t * 256 + b + j] = runR; runR += vr[j];
            }
        }
        totC[t] = runC; totR[t] = runR;
    }
    __syncthreads();
    if (t == 0) {
        int rc = 0, rr = 0;
        for (int k = 0; k < NBUCK; ++k) {
            estC[k] = rc; rc += totC[k];
            estR[k] = rr; rr += totR[k];
        }
        estC[NBUCK] = rc; estR[NBUCK] = rr;
    }
}

__global__ __launch_bounds__(256) void k_bscatter(
    const int* __restrict__ ei, const int* __restrict__ offC,
    const int* __restrict__ offR, const int* __restrict__ estC,
    const int* __restrict__ estR, unsigned* __restrict__ sortC,
    u16* __restrict__ sortR) {
    __shared__ int curC[NBUCK], curR[NBUCK];
    int b = blockIdx.x, t = threadIdx.x;
    if (t < NBUCK) {
        curC[t] = estC[t] + offC[t * 256 + b];
        curR[t] = estR[t] + offR[t * 256 + b];
    }
    __syncthreads();
    int base = b * EPB;
    for (int i = t; i < EPB; i += 256) {
        int r = ei[base + i];
        int c = ei[N_EDGES + base + i];
        int pc = atomicAdd(&curC[c >> 8], 1);
        sortC[pc] = ((unsigned)(c & 255) << 16) | (unsigned)r;  // r < 65536
        int pr = atomicAdd(&curR[r >> 8], 1);
        sortR[pr] = (u16)(r & 255);
    }
}

// per-bucket exact CSR + out-degree -> dis
__global__ __launch_bounds__(256) void k_bcsr(
    const unsigned* __restrict__ sortC, const int* __restrict__ estC,
    const u16* __restrict__ sortR, const int* __restrict__ estR,
    int* __restrict__ rowptr, int* __restrict__ rowend,
    int* __restrict__ srcl, float* __restrict__ dis) {
    __shared__ int hist[256], cur[256], excl[256], hist2[256];
    __shared__ int wsum[4], woff[4];
    __shared__ unsigned stg[BCAP];
    int k = blockIdx.x, t = threadIdx.x;
    int lane = t & 63, wid = t >> 6;
    int nloc = min(256, N_NODES - k * 256);
    int es = estC[k], ee = estC[k + 1];
    int ecnt = ee - es;
    int fs = es + k * 256;
    hist[t] = 0; cur[t] = 0; hist2[t] = 0;
    __syncthreads();
    for (int i = t; i < ecnt; i += 256)
        atomicAdd(&hist[sortC[es + i] >> 16], 1);
    {
        int rs = estR[k], rcnt = estR[k + 1] - rs;
        for (int i = t; i < rcnt; i += 256)
            atomicAdd(&hist2[(int)sortR[rs + i]], 1);
    }
    __syncthreads();
    if (t < nloc) dis[k * 256 + t] = rsqrtf((float)(hist2[t] + 1));
    int sv = hist[t] + (t < nloc ? 1 : 0);
    int sc = sv;
#pragma unroll
    for (int off = 1; off < 64; off <<= 1) {
        int y = __shfl_up(sc, off, 64);
        if (lane >= off) sc += y;
    }
    if (lane == 63) wsum[wid] = sc;
    __syncthreads();
    if (t == 0) {
        int r = 0;
#pragma unroll
        for (int w = 0; w < 4; ++w) { woff[w] = r; r += wsum[w]; }
    }
    __syncthreads();
    int ex = woff[wid] + sc - sv;
    excl[t] = ex;
    if (t < nloc) {
        rowptr[k * 256 + t] = fs + ex;
        rowend[k * 256 + t] = fs + ex + hist[t] + 1;
    }
    __syncthreads();
    int tot = ecnt + nloc;
    if (tot <= BCAP) {
        for (int i = t; i < ecnt; i += 256) {
            unsigned v = sortC[es + i];
            int j = v >> 16;
            int p = excl[j] + atomicAdd(&cur[j], 1);
            stg[p] = v & 0xffffu;
        }
        if (t < nloc) stg[excl[t] + hist[t]] = (unsigned)(k * 256 + t);
        __syncthreads();
        for (int i = t; i < tot; i += 256) srcl[fs + i] = (int)stg[i];
    } else {
        for (int i = t; i < ecnt; i += 256) {
            unsigned v = sortC[es + i];
            int j = v >> 16;
            int p = excl[j] + atomicAdd(&cur[j], 1);
            srcl[fs + p] = (int)(v & 0xffffu);
        }
        if (t < nloc) srcl[fs + excl[t] + hist[t]] = k * 256 + t;
    }
}

// ------------------------------------------------------------- MFMA GEMM
// out8 = fp8( dis[m] * ( A @ W + bias ) ).  BM=128, BN=256, BK=32.
// Linear 64B LDS rows; bank spread via XOR chunk swizzle on the per-lane
// GLOBAL source (LDS dest stays linear for global_load_lds) + on ds_reads.

template <bool SPLIT>
__global__ __launch_bounds__(256, 2) void k_gemm_mfma(
    const void* __restrict__ A0v, const float* __restrict__ A1,
    const u16* __restrict__ WT, const float* __restrict__ bias,
    const float* __restrict__ dis, u8* __restrict__ out8, int M) {
    __shared__ u16 As[128][32];
    __shared__ u16 Bs[256][32];
    const int t = threadIdx.x;
    const int m0 = blockIdx.x * 128;
    const int lane = t & 63, wave = t >> 6;
    const int wm = wave & 1, wn = wave >> 1;
    const int lr = lane & 15, kg = lane >> 4;

    f32x4 acc[4][8] = {};

    for (int k0 = 0; k0 < 256; k0 += 32) {
        if (SPLIT) {
#pragma unroll
            for (int i = 0; i < 2; ++i) {
                int idx = i * 256 + t;
                int row = idx >> 2, c = idx & 3;
                int cl = c ^ ((row >> 1) & 3);
                int grow = m0 + row;
                uint4 pk = {0u, 0u, 0u, 0u};
                if (grow < M) {
                    int k = k0 + cl * 8;
                    const float* src = (k < 128)
                        ? ((const float*)A0v + (size_t)grow * 128 + k)
                        : (A1 + (size_t)grow * 128 + (k - 128));
                    float4 f0 = *(const float4*)src;
                    float4 f1 = *(const float4*)(src + 4);
                    pk.x = f2bf(f0.x) | (f2bf(f0.y) << 16);
                    pk.y = f2bf(f0.z) | (f2bf(f0.w) << 16);
                    pk.z = f2bf(f1.x) | (f2bf(f1.y) << 16);
                    pk.w = f2bf(f1.z) | (f2bf(f1.w) << 16);
                }
                *(uint4*)&As[row][c * 8] = pk;
            }
        } else {
#pragma unroll
            for (int i = 0; i < 2; ++i) {
                int idx = i * 256 + t;
                int row = idx >> 2, c = idx & 3;
                int cl = c ^ ((row >> 1) & 3);
                const u16* src = (const u16*)A0v + (size_t)(m0 + row) * 256
                                 + k0 + cl * 8;
                __builtin_amdgcn_global_load_lds(
                    (const __attribute__((address_space(1))) void*)src,
                    (__attribute__((address_space(3))) void*)
                        ((char*)&As[0][0] + ((i * 256 + wave * 64) << 4)),
                    16, 0, 0);
            }
        }
#pragma unroll
        for (int i = 0; i < 4; ++i) {
            int idx = i * 256 + t;
            int row = idx >> 2, c = idx & 3;
            int cl = c ^ ((row >> 1) & 3);
            const u16* src = WT + (size_t)row * 256 + k0 + cl * 8;
            __builtin_amdgcn_global_load_lds(
                (const __attribute__((address_space(1))) void*)src,
                (__attribute__((address_space(3))) void*)
                    ((char*)&Bs[0][0] + ((i * 256 + wave * 64) << 4)),
                16, 0, 0);
        }
        __syncthreads();
        short8 af[4], bfr[8];
#pragma unroll
        for (int mi = 0; mi < 4; ++mi) {
            int row = wm * 64 + mi * 16 + lr;
            af[mi] = *(const short8*)&As[row][(kg ^ ((row >> 1) & 3)) * 8];
        }
#pragma unroll
        for (int ni = 0; ni < 8; ++ni) {
            int row = wn * 128 + ni * 16 + lr;
            bfr[ni] = *(const short8*)&Bs[row][(kg ^ ((row >> 1) & 3)) * 8];
        }
#pragma unroll
        for (int mi = 0; mi < 4; ++mi)
#pragma unroll
            for (int ni = 0; ni < 8; ++ni)
                acc[mi][ni] = __builtin_amdgcn_mfma_f32_16x16x32_bf16(
                    af[mi], bfr[ni], acc[mi][ni], 0, 0, 0);
        __syncthreads();
    }

    const int orow = m0 + wm * 64;
    const int ocol = wn * 128;
#pragma unroll
    for (int mi = 0; mi < 4; ++mi) {
#pragma unroll
        for (int r = 0; r < 4; ++r) {
            int row = orow + mi * 16 + kg * 4 + r;
            if (row >= M) continue;
            float d = dis[row];
#pragma unroll
            for (int ni = 0; ni < 8; ++ni) {
                int col = ocol + ni * 16 + lr;
                out8[(size_t)row * 256 + col] =
                    f2fp8(d * (acc[mi][ni][r] + bias[col]));
            }
        }
    }
}

// ----------------------------------------------------------- CSR aggregation
// fp8 rows (256B = 2 lines/edge). Wave per dst; half-wave covers the row with
// 8B/lane. LDS idx buffer holds PRE-SCALED byte offsets (src*256); batches of
// 32 edges (16/half in flight) with an adaptive 16-edge final batch to cut
// zero-row padding. Branch-free via zero-row padding (index N_NODES).

static __device__ __forceinline__ void addf8(uint2 v, f32x2* a) {
    a[0] += __builtin_amdgcn_cvt_pk_f32_fp8((int)v.x, false);  // v_pk_add_f32
    a[1] += __builtin_amdgcn_cvt_pk_f32_fp8((int)v.x, true);
    a[2] += __builtin_amdgcn_cvt_pk_f32_fp8((int)v.y, false);
    a[3] += __builtin_amdgcn_cvt_pk_f32_fp8((int)v.y, true);
}

static __device__ __forceinline__ void gather16_f8(
    const int* __restrict__ p, const u8* __restrict__ base, f32x2* a) {
    int4 q0 = *(const int4*)p;              // pre-scaled byte offsets
    int4 q1 = *(const int4*)(p + 4);
    int4 q2 = *(const int4*)(p + 8);
    int4 q3 = *(const int4*)(p + 12);
    uint2 v0  = *(const uint2*)(base + q0.x);
    uint2 v1  = *(const uint2*)(base + q0.y);
    uint2 v2  = *(const uint2*)(base + q0.z);
    uint2 v3  = *(const uint2*)(base + q0.w);
    uint2 v4  = *(const uint2*)(base + q1.x);
    uint2 v5  = *(const uint2*)(base + q1.y);
    uint2 v6  = *(const uint2*)(base + q1.z);
    uint2 v7  = *(const uint2*)(base + q1.w);
    uint2 v8  = *(const uint2*)(base + q2.x);
    uint2 v9  = *(const uint2*)(base + q2.y);
    uint2 v10 = *(const uint2*)(base + q2.z);
    uint2 v11 = *(const uint2*)(base + q2.w);
    uint2 v12 = *(const uint2*)(base + q3.x);
    uint2 v13 = *(const uint2*)(base + q3.y);
    uint2 v14 = *(const uint2*)(base + q3.z);
    uint2 v15 = *(const uint2*)(base + q3.w);
    addf8(v0, a);  addf8(v1, a);  addf8(v2, a);  addf8(v3, a);
    addf8(v4, a);  addf8(v5, a);  addf8(v6, a);  addf8(v7, a);
    addf8(v8, a);  addf8(v9, a);  addf8(v10, a); addf8(v11, a);
    addf8(v12, a); addf8(v13, a); addf8(v14, a); addf8(v15, a);
}

static __device__ __forceinline__ void gather8_f8(
    const int* __restrict__ p, const u8* __restrict__ base, f32x2* a) {
    int4 q0 = *(const int4*)p;
    int4 q1 = *(const int4*)(p + 4);
    uint2 v0 = *(const uint2*)(base + q0.x);
    uint2 v1 = *(const uint2*)(base + q0.y);
    uint2 v2 = *(const uint2*)(base + q0.z);
    uint2 v3 = *(const uint2*)(base + q0.w);
    uint2 v4 = *(const uint2*)(base + q1.x);
    uint2 v5 = *(const uint2*)(base + q1.y);
    uint2 v6 = *(const uint2*)(base + q1.z);
    uint2 v7 = *(const uint2*)(base + q1.w);
    addf8(v0, a); addf8(v1, a); addf8(v2, a); addf8(v3, a);
    addf8(v4, a); addf8(v5, a); addf8(v6, a); addf8(v7, a);
}

// process idxb[0..nn) (nn <= 64, buffer padded with zero-row offsets)
static __device__ __forceinline__ void gather_row(
    const int* __restrict__ idxb, int nn, int half,
    const u8* __restrict__ base, f32x2* a) {
    int j = 0;
    while (nn - j > 16) {                   // 32-edge batch (16 per half)
        gather16_f8(idxb + j + half * 16, base, a);
        j += 32;
    }
    if (j < nn)                              // 16-edge batch (8 per half)
        gather8_f8(idxb + j + half * 8, base, a);
}

__global__ __launch_bounds__(256) void k_agg_f8(
    const int* __restrict__ rowptr, const int* __restrict__ rowend,
    const int* __restrict__ srcl, const u8* __restrict__ hs,
    const float* __restrict__ dis, u16* __restrict__ out) {
    __shared__ int idxb[4][64];
    int wave = threadIdx.x >> 6;
    int lane = threadIdx.x & 63;
    int half = lane >> 5;
    int c8 = lane & 31;
    int dst = blockIdx.x * 4 + wave;
    if (dst >= N_NODES) return;
    int s = rowptr[dst], e = rowend[dst];
    const u8* base = hs + c8 * 8;
    f32x2 a[4] = {};
    for (int k0 = s; k0 < e; k0 += 64) {
        int kk = k0 + lane;
        int idx = (kk < e) ? __builtin_nontemporal_load(&srcl[kk]) : N_NODES;
        idxb[wave][lane] = idx << 8;        // pre-scaled byte offset
        gather_row(&idxb[wave][0], min(64, e - k0), half, base, a);
    }
    float r[8];
#pragma unroll
    for (int j = 0; j < 4; ++j) { r[2 * j] = a[j][0]; r[2 * j + 1] = a[j][1]; }
#pragma unroll
    for (int j = 0; j < 8; ++j) r[j] += __shfl_xor(r[j], 32, 64);
    if (half == 0) {
        float d = dis[dst];
        uint4 p;
        p.x = f2bf(fmaxf(r[0] * d, 0.f)) | (f2bf(fmaxf(r[1] * d, 0.f)) << 16);
        p.y = f2bf(fmaxf(r[2] * d, 0.f)) | (f2bf(fmaxf(r[3] * d, 0.f)) << 16);
        p.z = f2bf(fmaxf(r[4] * d, 0.f)) | (f2bf(fmaxf(r[5] * d, 0.f)) << 16);
        p.w = f2bf(fmaxf(r[6] * d, 0.f)) | (f2bf(fmaxf(r[7] * d, 0.f)) << 16);
        *(uint4*)&out[(size_t)dst * 256 + c8 * 8] = p;
    }
}

static __device__ __forceinline__ ull packmd(float v, int dstid) {
    return ((ull)__float_as_uint(v) << 32) | (unsigned)dstid;
}

__global__ __launch_bounds__(256) void k_agg_pool_f8(
    const int* __restrict__ rowptr, const int* __restrict__ rowend,
    const int* __restrict__ srcl, const u8* __restrict__ hs,
    const float* __restrict__ dis, ull* __restrict__ gpool) {
    __shared__ int idxb[4][64];
    __shared__ ull lm[4][256];
    int wave = threadIdx.x >> 6;
    int lane = threadIdx.x & 63;
    int half = lane >> 5;
    int c8 = lane & 31;
    const u8* base = hs + c8 * 8;
    float m[8] = {0.f, 0.f, 0.f, 0.f, 0.f, 0.f, 0.f, 0.f};
    int   ad[8] = {0, 0, 0, 0, 0, 0, 0, 0};
    for (int dst = blockIdx.x * 4 + wave; dst < N_NODES;
         dst += POOL_BLOCKS * 4) {
        int s = rowptr[dst], e = rowend[dst];
        f32x2 a[4] = {};
        for (int k0 = s; k0 < e; k0 += 64) {
            int kk = k0 + lane;
            int idx = (kk < e) ? __builtin_nontemporal_load(&srcl[kk])
                               : N_NODES;
            idxb[wave][lane] = idx << 8;
            gather_row(&idxb[wave][0], min(64, e - k0), half, base, a);
        }
        float d = dis[dst];
#pragma unroll
        for (int j = 0; j < 8; ++j) {
            float rj = (j & 1) ? a[j >> 1][1] : a[j >> 1][0];
            float v = (rj + __shfl_xor(rj, 32, 64)) * d;
            if (v > m[j]) { m[j] = v; ad[j] = dst; }
        }
    }
    if (half == 0) {
#pragma unroll
        for (int j = 0; j < 8; ++j) lm[wave][c8 * 8 + j] = packmd(m[j], ad[j]);
    }
    __syncthreads();
    int t = threadIdx.x;
    ull v = lm[0][t];
    v = (lm[1][t] > v) ? lm[1][t] : v;
    v = (lm[2][t] > v) ? lm[2][t] : v;
    v = (lm[3][t] > v) ? lm[3][t] : v;
    atomicMax(&gpool[t], v);
}

// exact repair from h2 + W2:  sum_src h3[src] = (sum_src dis[src]*h2[src])@W2
//                                              + b2 * sum_src dis[src]
__global__ __launch_bounds__(256) void k_fix(
    const ull* __restrict__ gpool, const int* __restrict__ rowptr,
    const int* __restrict__ rowend, const int* __restrict__ srcl,
    const u16* __restrict__ h2, const u16* __restrict__ W2T,
    const float* __restrict__ b2, const float* __restrict__ dis,
    float* __restrict__ g) {
    __shared__ float red[256];
    __shared__ int   sidx[128];
    __shared__ float sdis[128];
    __shared__ float Dsh;
    int b = blockIdx.x;                     // channel
    int t = threadIdx.x;                    // k index
    int dst = (int)(unsigned)(gpool[b] & 0xffffffffull);
    int s = rowptr[dst], e = rowend[dst];
    int n = e - s;
    float uk = 0.f;
    if (t == 0) Dsh = 0.f;
    for (int c0 = 0; c0 < n; c0 += 128) {
        int nn = min(128, n - c0);
        __syncthreads();
        for (int i = t; i < nn; i += 256) {
            int sr = srcl[s + c0 + i];
            sidx[i] = sr; sdis[i] = dis[sr];
        }
        __syncthreads();
        int i = 0;
        for (; i + 4 <= nn; i += 4) {
            float v0 = bflo((unsigned)h2[(size_t)sidx[i]     * 256 + t]);
            float v1 = bflo((unsigned)h2[(size_t)sidx[i + 1] * 256 + t]);
            float v2 = bflo((unsigned)h2[(size_t)sidx[i + 2] * 256 + t]);
            float v3 = bflo((unsigned)h2[(size_t)sidx[i + 3] * 256 + t]);
            uk += sdis[i] * v0 + sdis[i + 1] * v1
                + sdis[i + 2] * v2 + sdis[i + 3] * v3;
        }
        for (; i < nn; ++i)
            uk += sdis[i] * bflo((unsigned)h2[(size_t)sidx[i] * 256 + t]);
        if (t == 0) {
            float dl = 0.f;
            for (int q = 0; q < nn; ++q) dl += sdis[q];
            Dsh += dl;
        }
    }
    float w = bflo((unsigned)W2T[(size_t)b * 256 + t]);
    red[t] = uk * w;
    __syncthreads();
#pragma unroll
    for (int off = 128; off > 0; off >>= 1) {
        if (t < off) red[t] += red[t + off];
        __syncthreads();
    }
    if (t == 0) {
        float val = red[0] + b2[b] * Dsh;
        g[b] = fmaxf(dis[dst] * val, 0.f);
    }
}

// --------------------------------------------------------------------- head

__global__ __launch_bounds__(128) void k_head(
    const float* __restrict__ g, const float* __restrict__ Wp,
    const float* __restrict__ bp, const float* __restrict__ Wq,
    const float* __restrict__ bq, float* __restrict__ out) {
    __shared__ float sg[NHID];
    __shared__ float red[128];
    int t = threadIdx.x;
    sg[t] = g[t];
    sg[t + 128] = g[t + 128];
    __syncthreads();

    float v = 0.0f;
    if (t < NRES_P1) {
        float acc = bp[t];
        for (int k = 0; k < NHID; ++k) acc = fmaf(sg[k], Wp[k * NRES_P1 + t], acc);
        out[t] = acc;
        v = acc;
    }
    red[t] = (t < NRES_P1) ? v : -1e30f;
    __syncthreads();
#pragma unroll
    for (int off = 64; off > 0; off >>= 1) {
        if (t < off) red[t] = fmaxf(red[t], red[t + off]);
        __syncthreads();
    }
    float mx = red[0];
    __syncthreads();
    float ex = (t < NRES_P1) ? expf(v - mx) : 0.0f;
    red[t] = ex;
    __syncthreads();
#pragma unroll
    for (int off = 64; off > 0; off >>= 1) {
        if (t < off) red[t] += red[t + off];
        __syncthreads();
    }
    float sum = red[0];
    if (t < NRES_P1) out[NRES_P1 + t] = ex / sum;

    if (t < 64) {
        float a = fmaf(sg[t], Wq[t], 0.f);
        a = fmaf(sg[t + 64],  Wq[t + 64],  a);
        a = fmaf(sg[t + 128], Wq[t + 128], a);
        a = fmaf(sg[t + 192], Wq[t + 192], a);
#pragma unroll
        for (int off = 32; off > 0; off >>= 1) a += __shfl_down(a, off, 64);
        if (t == 0) out[2 * NRES_P1] = a + bq[0];
    }
}

// -------------------------------------------------------------------- launch

static inline size_t align256(size_t x) { return (x + 255) & ~size_t(255); }

extern "C" void kernel_launch(void* const* d_in, const int* in_sizes, int n_in,
                              void* d_out, int out_size, void* d_ws,
                              size_t ws_size, hipStream_t stream) {
    (void)in_sizes; (void)n_in; (void)out_size; (void)ws_size;
    const float* x    = (const float*)d_in[0];
    const float* feat = (const float*)d_in[1];
    const int*   ei   = (const int*)d_in[2];   // int32 (harness-converted)
    const float* W1   = (const float*)d_in[3];
    const float* b1   = (const float*)d_in[4];
    const float* W2   = (const float*)d_in[5];
    const float* b2   = (const float*)d_in[6];
    const float* Wp   = (const float*)d_in[7];
    const float* bp   = (const float*)d_in[8];
    const float* Wq   = (const float*)d_in[9];
    const float* bq   = (const float*)d_in[10];
    float* out = (float*)d_out;

    char* ws = (char*)d_ws;
    size_t off = 0;
    auto alloc = [&](size_t bytes) {
        void* p = ws + off;
        off = align256(off + bytes);
        return p;
    };
    int*   rowptr = (int*)alloc(4ull * N_NODES);
    int*   rowend = (int*)alloc(4ull * N_NODES);
    int*   srcl   = (int*)alloc(4ull * (N_EDGES + N_NODES));
    int*   estC   = (int*)alloc(4ull * (NBUCK + 1));
    int*   estR   = (int*)alloc(4ull * (NBUCK + 1));
    float* dis    = (float*)alloc(4ull * N_NODES);
    float* g      = (float*)alloc(4ull * NHID);
    ull*   gpool  = (ull*)alloc(8ull * NHID);
    u16*   W1T    = (u16*)alloc(2ull * 256 * 256);
    u16*   W2T    = (u16*)alloc(2ull * 256 * 256);
    u8*    buf1f8 = (u8*)alloc(1ull * (N_NODES + 1) * 256);  // h1 fp8 (+zero)
    u16*   buf2   = (u16*)alloc(2ull * N_NODES * 256);       // h2 bf16
    u8*    buf3f8 = (u8*)alloc(1ull * (N_NODES + 1) * 256);  // h3 fp8 (+zero)
    alloc(64 * 1024);   // tail guard: gemm2 A-tile OOB global_load_lds reads

    // transient sort buffers aliased into buf2 (dead before h2 is written)
    int*      pC    = (int*)buf2;                            // 256*196 ints
    int*      pR    = pC  + 256 * NBUCK;
    int*      offC  = pR  + 256 * NBUCK;
    int*      offR  = offC + 256 * NBUCK;
    unsigned* sortC = (unsigned*)(offR + 256 * NBUCK);       // 800k u32
    u16*      sortR = (u16*)(sortC + N_EDGES);               // 800k u16

    k_prep<<<320, 256, 0, stream>>>(ei, pC, pR, W1, W2, W1T, W2T, gpool,
                                    buf1f8 + (size_t)N_NODES * 256,
                                    buf3f8 + (size_t)N_NODES * 256);
    k_bscan<<<1, 256, 0, stream>>>(pC, pR, offC, offR, estC, estR);
    k_bscatter<<<256, 256, 0, stream>>>(ei, offC, offR, estC, estR,
                                        sortC, sortR);
    k_bcsr<<<NBUCK, 256, 0, stream>>>(sortC, estC, sortR, estR,
                                      rowptr, rowend, srcl, dis);

    const int gblocks = (N_NODES + 127) / 128;
    // conv1 linear -> h1 fp8
    k_gemm_mfma<true><<<gblocks, 256, 0, stream>>>(
        x, feat, W1T, b1, dis, buf1f8, N_NODES);
    // agg1: h2 = bf16(relu(dis .* gather-sum(h1 fp8)))
    k_agg_f8<<<(N_NODES + 3) / 4, 256, 0, stream>>>(rowptr, rowend, srcl,
                                                    buf1f8, dis, buf2);
    // conv2 linear -> h3 fp8
    k_gemm_mfma<false><<<gblocks, 256, 0, stream>>>(
        buf2, nullptr, W2T, b2, dis, buf3f8, N_NODES);
    // agg2 + pool: approx max + argmax via fp8
    k_agg_pool_f8<<<POOL_BLOCKS, 256, 0, stream>>>(rowptr, rowend, srcl,
                                                   buf3f8, dis, gpool);
    // exact repair of the winning dst per channel (from h2 + W2)
    k_fix<<<NHID, 256, 0, stream>>>(gpool, rowptr, rowend, srcl,
                                    buf2, W2T, b2, dis, g);

    k_head<<<1, 128, 0, stream>>>(g, Wp, bp, Wq, bq, out);
}

// Round 15
// 218.323 us; speedup vs baseline: 1.5426x; 1.0062x over previous
//
#include <hip/hip_runtime.h>

#define N_NODES 50000
#define N_EDGES 800000
#define NHID    256
#define NRES_P1 101

#define NBUCK   196            // node buckets (node >> 8), 50000/256 -> 196
#define EPB     3125           // edges per scatter block (256 blocks exactly)
#define BCAP    6144           // per-bucket staging cap
#define POOL_BLOCKS 2048       // fused agg2+pool grid

typedef unsigned short u16;
typedef unsigned char  u8;
typedef unsigned long long ull;
typedef __attribute__((ext_vector_type(8))) short short8;   // 8 bf16
typedef __attribute__((ext_vector_type(4))) float f32x4;
typedef __attribute__((ext_vector_type(2))) float f32x2;
typedef __attribute__((ext_vector_type(4))) unsigned uint32x4; // NT-store ok

static __device__ __forceinline__ unsigned f2bf(float f) {  // RNE -> low 16
    unsigned u = __float_as_uint(f);
    return (u + 0x7FFF + ((u >> 16) & 1)) >> 16;
}
static __device__ __forceinline__ float bflo(unsigned p) {
    return __uint_as_float(p << 16);
}
static __device__ __forceinline__ u8 f2fp8(float f) {       // HW e4m3 (OCP)
    return (u8)(__builtin_amdgcn_cvt_pk_fp8_f32(f, f, 0, false) & 0xff);
}

// ------------------------------------------ prep: bucket count + weight prep

__global__ __launch_bounds__(256) void k_prep(
    const int* __restrict__ ei, int* __restrict__ pC, int* __restrict__ pR,
    const float* __restrict__ W1, const float* __restrict__ W2,
    u16* __restrict__ W1T, u16* __restrict__ W2T,
    ull* __restrict__ gpool, u8* __restrict__ z1, u8* __restrict__ z2) {
    __shared__ int cC[NBUCK], cR[NBUCK];
    int b = blockIdx.x, t = threadIdx.x;
    if (b < 256) {
        if (t < NBUCK) { cC[t] = 0; cR[t] = 0; }
        __syncthreads();
        int base = b * EPB;
        for (int i = t; i < EPB; i += 256) {
            int r = ei[base + i];
            int c = ei[N_EDGES + base + i];
            atomicAdd(&cR[r >> 8], 1);
            atomicAdd(&cC[c >> 8], 1);
        }
        __syncthreads();
        if (t < NBUCK) { pC[b * NBUCK + t] = cC[t]; pR[b * NBUCK + t] = cR[t]; }
    } else {
        if (b == 256) {
            gpool[t] = 0ull;
            if (t < 64) {                         // 256B zero rows
                ((unsigned*)z1)[t] = 0u;
                ((unsigned*)z2)[t] = 0u;
            }
        }
        int tid = (b - 256) * 256 + t;            // 0..16383
        const float* W = (tid < 8192) ? W1 : W2;
        u16* WT = (tid < 8192) ? W1T : W2T;
        int id = tid & 8191;
        int n = id >> 5, k8 = (id & 31) << 3;
        u16 tmp[8];
#pragma unroll
        for (int i = 0; i < 8; ++i)
            tmp[i] = (u16)f2bf(W[(size_t)(k8 + i) * 256 + n]);
        *(uint4*)&WT[(size_t)n * 256 + k8] = *(uint4*)tmp;
    }
}

__global__ __launch_bounds__(256) void k_bscan(
    const int* __restrict__ pC, const int* __restrict__ pR,
    int* __restrict__ offC, int* __restrict__ offR,
    int* __restrict__ estC, int* __restrict__ estR) {
    __shared__ int totC[NBUCK], totR[NBUCK];
    int t = threadIdx.x;
    if (t < NBUCK) {
        int runC = 0, runR = 0;
        for (int b = 0; b < 256; b += 8) {
            int vc[8], vr[8];
#pragma unroll
            for (int j = 0; j < 8; ++j) {
                vc[j] = pC[(b + j) * NBUCK + t];
                vr[j] = pR[(b + j) * NBUCK + t];
            }
#pragma unroll
            for (int j = 0; j < 8; ++j) {
                offC[t * 256 + b + j] = runC; runC += vc[j];
                offR[t * 256 + b + j] = runR; runR += vr[j];
            }
        }
        totC[t] = runC; totR[t] = runR;
    }
    __syncthreads();
    if (t == 0) {
        int rc = 0, rr = 0;
        for (int k = 0; k < NBUCK; ++k) {
            estC[k] = rc; rc += totC[k];
            estR[k] = rr; rr += totR[k];
        }
        estC[NBUCK] = rc; estR[NBUCK] = rr;
    }
}

__global__ __launch_bounds__(256) void k_bscatter(
    const int* __restrict__ ei, const int* __restrict__ offC,
    const int* __restrict__ offR, const int* __restrict__ estC,
    const int* __restrict__ estR, unsigned* __restrict__ sortC,
    u16* __restrict__ sortR) {
    __shared__ int curC[NBUCK], curR[NBUCK];
    int b = blockIdx.x, t = threadIdx.x;
    if (t < NBUCK) {
        curC[t] = estC[t] + offC[t * 256 + b];
        curR[t] = estR[t] + offR[t * 256 + b];
    }
    __syncthreads();
    int base = b * EPB;
    for (int i = t; i < EPB; i += 256) {
        int r = ei[base + i];
        int c = ei[N_EDGES + base + i];
        int pc = atomicAdd(&curC[c >> 8], 1);
        sortC[pc] = ((unsigned)(c & 255) << 16) | (unsigned)r;  // r < 65536
        int pr = atomicAdd(&curR[r >> 8], 1);
        sortR[pr] = (u16)(r & 255);
    }
}

// per-bucket exact CSR + out-degree -> dis
__global__ __launch_bounds__(256) void k_bcsr(
    const unsigned* __restrict__ sortC, const int* __restrict__ estC,
    const u16* __restrict__ sortR, const int* __restrict__ estR,
    int* __restrict__ rowptr, int* __restrict__ rowend,
    int* __restrict__ srcl, float* __restrict__ dis) {
    __shared__ int hist[256], cur[256], excl[256], hist2[256];
    __shared__ int wsum[4], woff[4];
    __shared__ unsigned stg[BCAP];
    int k = blockIdx.x, t = threadIdx.x;
    int lane = t & 63, wid = t >> 6;
    int nloc = min(256, N_NODES - k * 256);
    int es = estC[k], ee = estC[k + 1];
    int ecnt = ee - es;
    int fs = es + k * 256;
    hist[t] = 0; cur[t] = 0; hist2[t] = 0;
    __syncthreads();
    for (int i = t; i < ecnt; i += 256)
        atomicAdd(&hist[sortC[es + i] >> 16], 1);
    {
        int rs = estR[k], rcnt = estR[k + 1] - rs;
        for (int i = t; i < rcnt; i += 256)
            atomicAdd(&hist2[(int)sortR[rs + i]], 1);
    }
    __syncthreads();
    if (t < nloc) dis[k * 256 + t] = rsqrtf((float)(hist2[t] + 1));
    int sv = hist[t] + (t < nloc ? 1 : 0);
    int sc = sv;
#pragma unroll
    for (int off = 1; off < 64; off <<= 1) {
        int y = __shfl_up(sc, off, 64);
        if (lane >= off) sc += y;
    }
    if (lane == 63) wsum[wid] = sc;
    __syncthreads();
    if (t == 0) {
        int r = 0;
#pragma unroll
        for (int w = 0; w < 4; ++w) { woff[w] = r; r += wsum[w]; }
    }
    __syncthreads();
    int ex = woff[wid] + sc - sv;
    excl[t] = ex;
    if (t < nloc) {
        rowptr[k * 256 + t] = fs + ex;
        rowend[k * 256 + t] = fs + ex + hist[t] + 1;
    }
    __syncthreads();
    int tot = ecnt + nloc;
    if (tot <= BCAP) {
        for (int i = t; i < ecnt; i += 256) {
            unsigned v = sortC[es + i];
            int j = v >> 16;
            int p = excl[j] + atomicAdd(&cur[j], 1);
            stg[p] = v & 0xffffu;
        }
        if (t < nloc) stg[excl[t] + hist[t]] = (unsigned)(k * 256 + t);
        __syncthreads();
        for (int i = t; i < tot; i += 256) srcl[fs + i] = (int)stg[i];
    } else {
        for (int i = t; i < ecnt; i += 256) {
            unsigned v = sortC[es + i];
            int j = v >> 16;
            int p = excl[j] + atomicAdd(&cur[j], 1);
            srcl[fs + p] = (int)(v & 0xffffu);
        }
        if (t < nloc) srcl[fs + excl[t] + hist[t]] = k * 256 + t;
    }
}

// ------------------------------------------------------------- MFMA GEMM
// out8 = fp8( dis[m] * ( A @ W + bias ) ).  BM=128, BN=256, BK=64 (4 K-steps
// -> half the barrier drains vs BK=32). Linear 128B LDS rows; bank spread via
// XOR chunk swizzle cl = c ^ (row&7) applied on the per-lane GLOBAL source
// (LDS dest stays linear for global_load_lds) + on fragment ds_reads.

template <bool SPLIT>
__global__ __launch_bounds__(256, 2) void k_gemm_mfma(
    const void* __restrict__ A0v, const float* __restrict__ A1,
    const u16* __restrict__ WT, const float* __restrict__ bias,
    const float* __restrict__ dis, u8* __restrict__ out8, int M) {
    __shared__ u16 As[128][64];
    __shared__ u16 Bs[256][64];
    const int t = threadIdx.x;
    const int m0 = blockIdx.x * 128;
    const int lane = t & 63, wave = t >> 6;
    const int wm = wave & 1, wn = wave >> 1;
    const int lr = lane & 15, kg = lane >> 4;

    f32x4 acc[4][8] = {};

    for (int k0 = 0; k0 < 256; k0 += 64) {
        // ---- A tile: 128 rows x 128B = 1024 chunks of 16B; 4 per thread
        if (SPLIT) {
#pragma unroll
            for (int i = 0; i < 4; ++i) {
                int idx = i * 256 + t;
                int row = idx >> 3, c = idx & 7;
                int cl = c ^ (row & 7);
                int grow = m0 + row;
                uint4 pk = {0u, 0u, 0u, 0u};
                if (grow < M) {
                    int k = k0 + cl * 8;            // 8-aligned, no straddle
                    const float* src = (k < 128)
                        ? ((const float*)A0v + (size_t)grow * 128 + k)
                        : (A1 + (size_t)grow * 128 + (k - 128));
                    float4 f0 = *(const float4*)src;
                    float4 f1 = *(const float4*)(src + 4);
                    pk.x = f2bf(f0.x) | (f2bf(f0.y) << 16);
                    pk.y = f2bf(f0.z) | (f2bf(f0.w) << 16);
                    pk.z = f2bf(f1.x) | (f2bf(f1.y) << 16);
                    pk.w = f2bf(f1.z) | (f2bf(f1.w) << 16);
                }
                *(uint4*)&As[row][c * 8] = pk;
            }
        } else {
#pragma unroll
            for (int i = 0; i < 4; ++i) {
                int idx = i * 256 + t;
                int row = idx >> 3, c = idx & 7;
                int cl = c ^ (row & 7);
                const u16* src = (const u16*)A0v + (size_t)(m0 + row) * 256
                                 + k0 + cl * 8;
                __builtin_amdgcn_global_load_lds(
                    (const __attribute__((address_space(1))) void*)src,
                    (__attribute__((address_space(3))) void*)
                        ((char*)&As[0][0] + ((i * 256 + wave * 64) << 4)),
                    16, 0, 0);
            }
        }
        // ---- B tile: 256 rows x 128B = 2048 chunks; 8 per thread
#pragma unroll
        for (int i = 0; i < 8; ++i) {
            int idx = i * 256 + t;
            int row = idx >> 3, c = idx & 7;
            int cl = c ^ (row & 7);
            const u16* src = WT + (size_t)row * 256 + k0 + cl * 8;
            __builtin_amdgcn_global_load_lds(
                (const __attribute__((address_space(1))) void*)src,
                (__attribute__((address_space(3))) void*)
                    ((char*)&Bs[0][0] + ((i * 256 + wave * 64) << 4)),
                16, 0, 0);
        }
        __syncthreads();
#pragma unroll
        for (int kh = 0; kh < 2; ++kh) {        // two K=32 halves per step
            short8 af[4], bfr[8];
            int q = kg + kh * 4;                // logical 16B chunk
#pragma unroll
            for (int mi = 0; mi < 4; ++mi) {
                int row = wm * 64 + mi * 16 + lr;
                af[mi] = *(const short8*)&As[row][(q ^ (row & 7)) * 8];
            }
#pragma unroll
            for (int ni = 0; ni < 8; ++ni) {
                int row = wn * 128 + ni * 16 + lr;
                bfr[ni] = *(const short8*)&Bs[row][(q ^ (row & 7)) * 8];
            }
#pragma unroll
            for (int mi = 0; mi < 4; ++mi)
#pragma unroll
                for (int ni = 0; ni < 8; ++ni)
                    acc[mi][ni] = __builtin_amdgcn_mfma_f32_16x16x32_bf16(
                        af[mi], bfr[ni], acc[mi][ni], 0, 0, 0);
        }
        __syncthreads();
    }

    const int orow = m0 + wm * 64;
    const int ocol = wn * 128;
#pragma unroll
    for (int mi = 0; mi < 4; ++mi) {
#pragma unroll
        for (int r = 0; r < 4; ++r) {
            int row = orow + mi * 16 + kg * 4 + r;
            if (row >= M) continue;
            float d = dis[row];
#pragma unroll
            for (int ni = 0; ni < 8; ++ni) {
                int col = ocol + ni * 16 + lr;
                out8[(size_t)row * 256 + col] =
                    f2fp8(d * (acc[mi][ni][r] + bias[col]));
            }
        }
    }
}

// ----------------------------------------------------------- CSR aggregation

static __device__ __forceinline__ void addf8(uint2 v, f32x2* a) {
    a[0] += __builtin_amdgcn_cvt_pk_f32_fp8((int)v.x, false);  // v_pk_add_f32
    a[1] += __builtin_amdgcn_cvt_pk_f32_fp8((int)v.x, true);
    a[2] += __builtin_amdgcn_cvt_pk_f32_fp8((int)v.y, false);
    a[3] += __builtin_amdgcn_cvt_pk_f32_fp8((int)v.y, true);
}

static __device__ __forceinline__ void gather16_f8(
    const int* __restrict__ p, const u8* __restrict__ base, f32x2* a) {
    int4 q0 = *(const int4*)p;              // pre-scaled byte offsets
    int4 q1 = *(const int4*)(p + 4);
    int4 q2 = *(const int4*)(p + 8);
    int4 q3 = *(const int4*)(p + 12);
    uint2 v0  = *(const uint2*)(base + q0.x);
    uint2 v1  = *(const uint2*)(base + q0.y);
    uint2 v2  = *(const uint2*)(base + q0.z);
    uint2 v3  = *(const uint2*)(base + q0.w);
    uint2 v4  = *(const uint2*)(base + q1.x);
    uint2 v5  = *(const uint2*)(base + q1.y);
    uint2 v6  = *(const uint2*)(base + q1.z);
    uint2 v7  = *(const uint2*)(base + q1.w);
    uint2 v8  = *(const uint2*)(base + q2.x);
    uint2 v9  = *(const uint2*)(base + q2.y);
    uint2 v10 = *(const uint2*)(base + q2.z);
    uint2 v11 = *(const uint2*)(base + q2.w);
    uint2 v12 = *(const uint2*)(base + q3.x);
    uint2 v13 = *(const uint2*)(base + q3.y);
    uint2 v14 = *(const uint2*)(base + q3.z);
    uint2 v15 = *(const uint2*)(base + q3.w);
    addf8(v0, a);  addf8(v1, a);  addf8(v2, a);  addf8(v3, a);
    addf8(v4, a);  addf8(v5, a);  addf8(v6, a);  addf8(v7, a);
    addf8(v8, a);  addf8(v9, a);  addf8(v10, a); addf8(v11, a);
    addf8(v12, a); addf8(v13, a); addf8(v14, a); addf8(v15, a);
}

static __device__ __forceinline__ void gather8_f8(
    const int* __restrict__ p, const u8* __restrict__ base, f32x2* a) {
    int4 q0 = *(const int4*)p;
    int4 q1 = *(const int4*)(p + 4);
    uint2 v0 = *(const uint2*)(base + q0.x);
    uint2 v1 = *(const uint2*)(base + q0.y);
    uint2 v2 = *(const uint2*)(base + q0.z);
    uint2 v3 = *(const uint2*)(base + q0.w);
    uint2 v4 = *(const uint2*)(base + q1.x);
    uint2 v5 = *(const uint2*)(base + q1.y);
    uint2 v6 = *(const uint2*)(base + q1.z);
    uint2 v7 = *(const uint2*)(base + q1.w);
    addf8(v0, a); addf8(v1, a); addf8(v2, a); addf8(v3, a);
    addf8(v4, a); addf8(v5, a); addf8(v6, a); addf8(v7, a);
}

static __device__ __forceinline__ void gather_row(
    const int* __restrict__ idxb, int nn, int half,
    const u8* __restrict__ base, f32x2* a) {
    int j = 0;
    while (nn - j > 16) {                   // 32-edge batch (16 per half)
        gather16_f8(idxb + j + half * 16, base, a);
        j += 32;
    }
    if (j < nn)                              // 16-edge batch (8 per half)
        gather8_f8(idxb + j + half * 8, base, a);
}

__global__ __launch_bounds__(256) void k_agg_f8(
    const int* __restrict__ rowptr, const int* __restrict__ rowend,
    const int* __restrict__ srcl, const u8* __restrict__ hs,
    const float* __restrict__ dis, u16* __restrict__ out) {
    __shared__ int idxb[4][64];
    int wave = threadIdx.x >> 6;
    int lane = threadIdx.x & 63;
    int half = lane >> 5;
    int c8 = lane & 31;
    int dst = blockIdx.x * 4 + wave;
    if (dst >= N_NODES) return;
    int s = rowptr[dst], e = rowend[dst];
    const u8* base = hs + c8 * 8;
    f32x2 a[4] = {};
    for (int k0 = s; k0 < e; k0 += 64) {
        int kk = k0 + lane;
        int idx = (kk < e) ? __builtin_nontemporal_load(&srcl[kk]) : N_NODES;
        idxb[wave][lane] = idx << 8;        // pre-scaled byte offset
        gather_row(&idxb[wave][0], min(64, e - k0), half, base, a);
    }
    float r[8];
#pragma unroll
    for (int j = 0; j < 4; ++j) { r[2 * j] = a[j][0]; r[2 * j + 1] = a[j][1]; }
#pragma unroll
    for (int j = 0; j < 8; ++j) r[j] += __shfl_xor(r[j], 32, 64);
    if (half == 0) {
        float d = dis[dst];
        uint32x4 p;
        p.x = f2bf(fmaxf(r[0] * d, 0.f)) | (f2bf(fmaxf(r[1] * d, 0.f)) << 16);
        p.y = f2bf(fmaxf(r[2] * d, 0.f)) | (f2bf(fmaxf(r[3] * d, 0.f)) << 16);
        p.z = f2bf(fmaxf(r[4] * d, 0.f)) | (f2bf(fmaxf(r[5] * d, 0.f)) << 16);
        p.w = f2bf(fmaxf(r[6] * d, 0.f)) | (f2bf(fmaxf(r[7] * d, 0.f)) << 16);
        // NT store: keep h1 resident in L2 during the gather (h2 is consumed
        // later as a dense stream by gemm2 — L3 is fine for that)
        __builtin_nontemporal_store(
            p, (uint32x4*)&out[(size_t)dst * 256 + c8 * 8]);
    }
}

static __device__ __forceinline__ ull packmd(float v, int dstid) {
    return ((ull)__float_as_uint(v) << 32) | (unsigned)dstid;
}

__global__ __launch_bounds__(256) void k_agg_pool_f8(
    const int* __restrict__ rowptr, const int* __restrict__ rowend,
    const int* __restrict__ srcl, const u8* __restrict__ hs,
    const float* __restrict__ dis, ull* __restrict__ gpool) {
    __shared__ int idxb[4][64];
    __shared__ ull lm[4][256];
    int wave = threadIdx.x >> 6;
    int lane = threadIdx.x & 63;
    int half = lane >> 5;
    int c8 = lane & 31;
    const u8* base = hs + c8 * 8;
    float m[8] = {0.f, 0.f, 0.f, 0.f, 0.f, 0.f, 0.f, 0.f};
    int   ad[8] = {0, 0, 0, 0, 0, 0, 0, 0};
    for (int dst = blockIdx.x * 4 + wave; dst < N_NODES;
         dst += POOL_BLOCKS * 4) {
        int s = rowptr[dst], e = rowend[dst];
        f32x2 a[4] = {};
        for (int k0 = s; k0 < e; k0 += 64) {
            int kk = k0 + lane;
            int idx = (kk < e) ? __builtin_nontemporal_load(&srcl[kk])
                               : N_NODES;
            idxb[wave][lane] = idx << 8;
            gather_row(&idxb[wave][0], min(64, e - k0), half, base, a);
        }
        float d = dis[dst];
#pragma unroll
        for (int j = 0; j < 8; ++j) {
            float rj = (j & 1) ? a[j >> 1][1] : a[j >> 1][0];
            float v = (rj + __shfl_xor(rj, 32, 64)) * d;
            if (v > m[j]) { m[j] = v; ad[j] = dst; }
        }
    }
    if (half == 0) {
#pragma unroll
        for (int j = 0; j < 8; ++j) lm[wave][c8 * 8 + j] = packmd(m[j], ad[j]);
    }
    __syncthreads();
    int t = threadIdx.x;
    ull v = lm[0][t];
    v = (lm[1][t] > v) ? lm[1][t] : v;
    v = (lm[2][t] > v) ? lm[2][t] : v;
    v = (lm[3][t] > v) ? lm[3][t] : v;
    atomicMax(&gpool[t], v);
}

// exact repair from h2 + W2:  sum_src h3[src] = (sum_src dis[src]*h2[src])@W2
//                                              + b2 * sum_src dis[src]
__global__ __launch_bounds__(256) void k_fix(
    const ull* __restrict__ gpool, const int* __restrict__ rowptr,
    const int* __restrict__ rowend, const int* __restrict__ srcl,
    const u16* __restrict__ h2, const u16* __restrict__ W2T,
    const float* __restrict__ b2, const float* __restrict__ dis,
    float* __restrict__ g) {
    __shared__ float red[256];
    __shared__ int   sidx[128];
    __shared__ float sdis[128];
    __shared__ float Dsh;
    int b = blockIdx.x;                     // channel
    int t = threadIdx.x;                    // k index
    int dst = (int)(unsigned)(gpool[b] & 0xffffffffull);
    int s = rowptr[dst], e = rowend[dst];
    int n = e - s;
    float uk = 0.f;
    if (t == 0) Dsh = 0.f;
    for (int c0 = 0; c0 < n; c0 += 128) {
        int nn = min(128, n - c0);
        __syncthreads();
        for (int i = t; i < nn; i += 256) {
            int sr = srcl[s + c0 + i];
            sidx[i] = sr; sdis[i] = dis[sr];
        }
        __syncthreads();
        int i = 0;
        for (; i + 4 <= nn; i += 4) {
            float v0 = bflo((unsigned)h2[(size_t)sidx[i]     * 256 + t]);
            float v1 = bflo((unsigned)h2[(size_t)sidx[i + 1] * 256 + t]);
            float v2 = bflo((unsigned)h2[(size_t)sidx[i + 2] * 256 + t]);
            float v3 = bflo((unsigned)h2[(size_t)sidx[i + 3] * 256 + t]);
            uk += sdis[i] * v0 + sdis[i + 1] * v1
                + sdis[i + 2] * v2 + sdis[i + 3] * v3;
        }
        for (; i < nn; ++i)
            uk += sdis[i] * bflo((unsigned)h2[(size_t)sidx[i] * 256 + t]);
        if (t == 0) {
            float dl = 0.f;
            for (int q = 0; q < nn; ++q) dl += sdis[q];
            Dsh += dl;
        }
    }
    float w = bflo((unsigned)W2T[(size_t)b * 256 + t]);
    red[t] = uk * w;
    __syncthreads();
#pragma unroll
    for (int off = 128; off > 0; off >>= 1) {
        if (t < off) red[t] += red[t + off];
        __syncthreads();
    }
    if (t == 0) {
        float val = red[0] + b2[b] * Dsh;
        g[b] = fmaxf(dis[dst] * val, 0.f);
    }
}

// --------------------------------------------------------------------- head

__global__ __launch_bounds__(128) void k_head(
    const float* __restrict__ g, const float* __restrict__ Wp,
    const float* __restrict__ bp, const float* __restrict__ Wq,
    const float* __restrict__ bq, float* __restrict__ out) {
    __shared__ float sg[NHID];
    __shared__ float red[128];
    int t = threadIdx.x;
    sg[t] = g[t];
    sg[t + 128] = g[t + 128];
    __syncthreads();

    float v = 0.0f;
    if (t < NRES_P1) {
        float acc = bp[t];
        for (int k = 0; k < NHID; ++k) acc = fmaf(sg[k], Wp[k * NRES_P1 + t], acc);
        out[t] = acc;
        v = acc;
    }
    red[t] = (t < NRES_P1) ? v : -1e30f;
    __syncthreads();
#pragma unroll
    for (int off = 64; off > 0; off >>= 1) {
        if (t < off) red[t] = fmaxf(red[t], red[t + off]);
        __syncthreads();
    }
    float mx = red[0];
    __syncthreads();
    float ex = (t < NRES_P1) ? expf(v - mx) : 0.0f;
    red[t] = ex;
    __syncthreads();
#pragma unroll
    for (int off = 64; off > 0; off >>= 1) {
        if (t < off) red[t] += red[t + off];
        __syncthreads();
    }
    float sum = red[0];
    if (t < NRES_P1) out[NRES_P1 + t] = ex / sum;

    if (t < 64) {
        float a = fmaf(sg[t], Wq[t], 0.f);
        a = fmaf(sg[t + 64],  Wq[t + 64],  a);
        a = fmaf(sg[t + 128], Wq[t + 128], a);
        a = fmaf(sg[t + 192], Wq[t + 192], a);
#pragma unroll
        for (int off = 32; off > 0; off >>= 1) a += __shfl_down(a, off, 64);
        if (t == 0) out[2 * NRES_P1] = a + bq[0];
    }
}

// -------------------------------------------------------------------- launch

static inline size_t align256(size_t x) { return (x + 255) & ~size_t(255); }

extern "C" void kernel_launch(void* const* d_in, const int* in_sizes, int n_in,
                              void* d_out, int out_size, void* d_ws,
                              size_t ws_size, hipStream_t stream) {
    (void)in_sizes; (void)n_in; (void)out_size; (void)ws_size;
    const float* x    = (const float*)d_in[0];
    const float* feat = (const float*)d_in[1];
    const int*   ei   = (const int*)d_in[2];   // int32 (harness-converted)
    const float* W1   = (const float*)d_in[3];
    const float* b1   = (const float*)d_in[4];
    const float* W2   = (const float*)d_in[5];
    const float* b2   = (const float*)d_in[6];
    const float* Wp   = (const float*)d_in[7];
    const float* bp   = (const float*)d_in[8];
    const float* Wq   = (const float*)d_in[9];
    const float* bq   = (const float*)d_in[10];
    float* out = (float*)d_out;

    char* ws = (char*)d_ws;
    size_t off = 0;
    auto alloc = [&](size_t bytes) {
        void* p = ws + off;
        off = align256(off + bytes);
        return p;
    };
    int*   rowptr = (int*)alloc(4ull * N_NODES);
    int*   rowend = (int*)alloc(4ull * N_NODES);
    int*   srcl   = (int*)alloc(4ull * (N_EDGES + N_NODES));
    int*   estC   = (int*)alloc(4ull * (NBUCK + 1));
    int*   estR   = (int*)alloc(4ull * (NBUCK + 1));
    float* dis    = (float*)alloc(4ull * N_NODES);
    float* g      = (float*)alloc(4ull * NHID);
    ull*   gpool  = (ull*)alloc(8ull * NHID);
    u16*   W1T    = (u16*)alloc(2ull * 256 * 256);
    u16*   W2T    = (u16*)alloc(2ull * 256 * 256);
    u8*    buf1f8 = (u8*)alloc(1ull * (N_NODES + 1) * 256);  // h1 fp8 (+zero)
    u16*   buf2   = (u16*)alloc(2ull * N_NODES * 256);       // h2 bf16
    u8*    buf3f8 = (u8*)alloc(1ull * (N_NODES + 1) * 256);  // h3 fp8 (+zero)
    alloc(64 * 1024);   // tail guard: gemm2 A-tile OOB global_load_lds reads

    // transient sort buffers aliased into buf2 (dead before h2 is written)
    int*      pC    = (int*)buf2;                            // 256*196 ints
    int*      pR    = pC  + 256 * NBUCK;
    int*      offC  = pR  + 256 * NBUCK;
    int*      offR  = offC + 256 * NBUCK;
    unsigned* sortC = (unsigned*)(offR + 256 * NBUCK);       // 800k u32
    u16*      sortR = (u16*)(sortC + N_EDGES);               // 800k u16

    k_prep<<<320, 256, 0, stream>>>(ei, pC, pR, W1, W2, W1T, W2T, gpool,
                                    buf1f8 + (size_t)N_NODES * 256,
                                    buf3f8 + (size_t)N_NODES * 256);
    k_bscan<<<1, 256, 0, stream>>>(pC, pR, offC, offR, estC, estR);
    k_bscatter<<<256, 256, 0, stream>>>(ei, offC, offR, estC, estR,
                                        sortC, sortR);
    k_bcsr<<<NBUCK, 256, 0, stream>>>(sortC, estC, sortR, estR,
                                      rowptr, rowend, srcl, dis);

    const int gblocks = (N_NODES + 127) / 128;
    // conv1 linear -> h1 fp8
    k_gemm_mfma<true><<<gblocks, 256, 0, stream>>>(
        x, feat, W1T, b1, dis, buf1f8, N_NODES);
    // agg1: h2 = bf16(relu(dis .* gather-sum(h1 fp8)))
    k_agg_f8<<<(N_NODES + 3) / 4, 256, 0, stream>>>(rowptr, rowend, srcl,
                                                    buf1f8, dis, buf2);
    // conv2 linear -> h3 fp8
    k_gemm_mfma<false><<<gblocks, 256, 0, stream>>>(
        buf2, nullptr, W2T, b2, dis, buf3f8, N_NODES);
    // agg2 + pool: approx max + argmax via fp8
    k_agg_pool_f8<<<POOL_BLOCKS, 256, 0, stream>>>(rowptr, rowend, srcl,
                                                   buf3f8, dis, gpool);
    // exact repair of the winning dst per channel (from h2 + W2)
    k_fix<<<NHID, 256, 0, stream>>>(gpool, rowptr, rowend, srcl,
                                    buf2, W2T, b2, dis, g);

    k_head<<<1, 128, 0, stream>>>(g, Wp, bp, Wq, bq, out);
}